// Round 7
// baseline (173.933 us; speedup 1.0000x reference)
//
#include <hip/hip_runtime.h>
#include <hip/hip_bf16.h>
#include <stdint.h>

// Problem constants: B=2, S=2048, D_MODEL=1024, H=16, Dk=64. M = B*S = 4096.
typedef unsigned short u16;
typedef __attribute__((ext_vector_type(8))) short short8;
typedef __attribute__((ext_vector_type(8))) __bf16 bf16x8;
typedef __attribute__((ext_vector_type(4))) float f32x4;
typedef __attribute__((ext_vector_type(4))) uint32_t u32x4;

#if defined(__has_builtin)
#if __has_builtin(__builtin_amdgcn_global_load_lds)
#define USE_GLLDS 1
#endif
#endif

// Fast 2^x: v_exp_f32 is the native HW op. (__exp2f collides with glibc.)
#if defined(__has_builtin)
#if __has_builtin(__builtin_amdgcn_exp2f)
#define HAVE_EXP2_BUILTIN 1
#endif
#endif
__device__ __forceinline__ float fexp2(float x) {
#ifdef HAVE_EXP2_BUILTIN
  return __builtin_amdgcn_exp2f(x);
#else
  return exp2f(x);
#endif
}

__device__ __forceinline__ u16 f2bf(float f) {
  __hip_bfloat16 h = __float2bfloat16(f);
  return __builtin_bit_cast(u16, h);
}

__device__ __forceinline__ f32x4 mfma16(bf16x8 a, bf16x8 b, f32x4 c) {
  return __builtin_amdgcn_mfma_f32_16x16x32_bf16(a, b, c, 0, 0, 0);
}

#ifdef USE_GLLDS
__device__ __forceinline__ void async_cp16(const void* g, void* l) {
  __builtin_amdgcn_global_load_lds(
      (const __attribute__((address_space(1))) void*)g,
      (__attribute__((address_space(3))) void*)l, 16, 0, 0);
}
#endif

// ---------------------------------------------------------------------------
// Kernel 1: fp32 -> bf16 conversion of q,k,v (4M each) and w_q,w_k,w_v,w_o (1M
// each) into one contiguous 16M-element bf16 region at the start of d_ws.
// ---------------------------------------------------------------------------
__global__ __launch_bounds__(256) void cvt_all(
    const float* __restrict__ q, const float* __restrict__ k,
    const float* __restrict__ v, const float* __restrict__ w0,
    const float* __restrict__ w1, const float* __restrict__ w2,
    const float* __restrict__ w3, u16* __restrict__ dst) {
  size_t i = ((size_t)blockIdx.x * 256 + threadIdx.x) * 8;
  const size_t M1 = 1u << 20;
  const float* s;
  size_t base;
  if (i < 4 * M1) { s = q; base = 0; }
  else if (i < 8 * M1) { s = k; base = 4 * M1; }
  else if (i < 12 * M1) { s = v; base = 8 * M1; }
  else if (i < 13 * M1) { s = w0; base = 12 * M1; }
  else if (i < 14 * M1) { s = w1; base = 13 * M1; }
  else if (i < 15 * M1) { s = w2; base = 14 * M1; }
  else { s = w3; base = 15 * M1; }
  const float4 a = *(const float4*)(s + (i - base));
  const float4 b = *(const float4*)(s + (i - base) + 4);
  short8 r;
  r[0] = (short)f2bf(a.x); r[1] = (short)f2bf(a.y);
  r[2] = (short)f2bf(a.z); r[3] = (short)f2bf(a.w);
  r[4] = (short)f2bf(b.x); r[5] = (short)f2bf(b.y);
  r[6] = (short)f2bf(b.z); r[7] = (short)f2bf(b.w);
  *(short8*)(dst + i) = r;
}

// ---------------------------------------------------------------------------
// GEMM: C[M=4096, N=1024] = X[4096,1024] * W[1024,1024]^T + bias.
// 128x128 tile, BK=64, 4 waves. Epilogue modes:
//   0: Q  -> bf16 split-head [B,H,S,64], scaled by 0.125*log2(e)  (exp2 dom.)
//   1: K  -> bf16 split-head [B,H,S,64]
//   2: V  -> bf16 TRANSPOSED split-head [B,H,64,S]  (V^T for the PV mfma)
//   3: fp32 row-major [4096,1024] (output projection)
// ---------------------------------------------------------------------------
__device__ __forceinline__ void gemm_body(const u16* __restrict__ X,
                                          const u16* __restrict__ W,
                                          const float* __restrict__ bias,
                                          void* __restrict__ outp, int mode) {
  __shared__ u16 Al[128 * 64];
  __shared__ u16 Bl[128 * 64];
  const int tid = threadIdx.x;
  const int wv = tid >> 6, l = tid & 63;
  const int wr = wv >> 1, wc = wv & 1;
  const int m0 = blockIdx.y * 128, n0 = blockIdx.x * 128;
  const int lrow = l & 15, lk = (l >> 4) * 8;

  f32x4 acc[4][4];
#pragma unroll
  for (int i = 0; i < 4; ++i)
#pragma unroll
    for (int j = 0; j < 4; ++j) acc[i][j] = (f32x4){0.f, 0.f, 0.f, 0.f};

  const u16* Asrc = X + (size_t)(m0 + (tid >> 3)) * 1024 + (tid & 7) * 8;
  const u16* Bsrc = W + (size_t)(n0 + (tid >> 3)) * 1024 + (tid & 7) * 8;

  for (int kt = 0; kt < 1024; kt += 64) {
#ifdef USE_GLLDS
#pragma unroll
    for (int p = 0; p < 4; ++p) {
      async_cp16(Asrc + (size_t)p * 32 * 1024 + kt, &Al[p * 2048 + wv * 512]);
      async_cp16(Bsrc + (size_t)p * 32 * 1024 + kt, &Bl[p * 2048 + wv * 512]);
    }
#else
    short8 ar[4], br[4];
#pragma unroll
    for (int p = 0; p < 4; ++p) {
      ar[p] = *(const short8*)(Asrc + (size_t)p * 32 * 1024 + kt);
      br[p] = *(const short8*)(Bsrc + (size_t)p * 32 * 1024 + kt);
    }
#pragma unroll
    for (int p = 0; p < 4; ++p) {
      *(short8*)&Al[p * 2048 + tid * 8] = ar[p];
      *(short8*)&Bl[p * 2048 + tid * 8] = br[p];
    }
#endif
    __syncthreads();
#pragma unroll
    for (int ks = 0; ks < 2; ++ks) {
      bf16x8 af[4], bf[4];
#pragma unroll
      for (int mf = 0; mf < 4; ++mf)
        af[mf] = *(const bf16x8*)&Al[(wr * 64 + mf * 16 + lrow) * 64 + ks * 32 + lk];
#pragma unroll
      for (int nf = 0; nf < 4; ++nf)
        bf[nf] = *(const bf16x8*)&Bl[(wc * 64 + nf * 16 + lrow) * 64 + ks * 32 + lk];
#pragma unroll
      for (int mf = 0; mf < 4; ++mf)
#pragma unroll
        for (int nf = 0; nf < 4; ++nf)
          acc[mf][nf] = mfma16(af[mf], bf[nf], acc[mf][nf]);
    }
    __syncthreads();
  }

  const int rb = (l >> 4) * 4;
#pragma unroll
  for (int mf = 0; mf < 4; ++mf) {
#pragma unroll
    for (int nf = 0; nf < 4; ++nf) {
      const int gn = n0 + wc * 64 + nf * 16 + lrow;
      const float bi = bias[gn];
#pragma unroll
      for (int r = 0; r < 4; ++r) {
        const int gm = m0 + wr * 64 + mf * 16 + rb + r;
        float val = acc[mf][nf][r] + bi;
        const int b = gm >> 11, s = gm & 2047, h = gn >> 6, d = gn & 63;
        if (mode == 3) {
          ((float*)outp)[(size_t)gm * 1024 + gn] = val;
        } else if (mode == 2) {
          // V^T: [B,H,64,S]
          ((u16*)outp)[(((size_t)((b * 16 + h) * 64 + d)) << 11) + s] = f2bf(val);
        } else {
          if (mode == 0) val *= 0.18033688f;  // (1/8)*log2(e): exp2-domain
          ((u16*)outp)[(((size_t)((b * 16 + h) * 2048 + s)) << 6) + d] = f2bf(val);
        }
      }
    }
  }
}

__global__ __launch_bounds__(256) void gemm_proj(
    const u16* __restrict__ qb, const u16* __restrict__ wqb,
    const float* __restrict__ b_q, const float* __restrict__ b_k,
    const float* __restrict__ b_v, u16* __restrict__ Qh) {
  const int z = blockIdx.z;
  const float* bias = (z == 0) ? b_q : ((z == 1) ? b_k : b_v);
  gemm_body(qb + ((size_t)z << 22), wqb + ((size_t)z << 20), bias,
            Qh + ((size_t)z << 22), z);
}

__global__ __launch_bounds__(256) void gemm_out(
    const u16* __restrict__ X, const u16* __restrict__ W,
    const float* __restrict__ bias, float* __restrict__ out) {
  gemm_body(X, W, bias, out, 3);
}

// ---------------------------------------------------------------------------
// Flash attention v3: swapped-operand + split-KV(2) + single-buffer K/V LDS.
//   S' = mfma(A=K, B=Q*scale*log2e) -> D[k][q], lane holds q = l&15
//   softmax in exp2 domain, defer-max (THR=8 log2-units)
//   O^T = mfma(A=V^T, B=P) -> D[d][q]
// Grid (16, 32, 2): z = KV half (16 tiles each). Block = 8 waves x 16 q-rows.
// LDS 34KB -> 4 blocks/CU = 32 waves/CU; TLP hides single-buffer staging.
// P slab: per-wave 16 rows x 36 dwords (32 payload + 4 pad; footprint of the
// writes is indices 0..31 -- stride MUST be >= 32; 20 was the round-6 bug).
// Writes NORMALIZED bf16 partial O + (m, ls) per row; combine() merges.
// ---------------------------------------------------------------------------
__global__ __launch_bounds__(512, 4) void flash_attn3(
    const u16* __restrict__ Qh, const u16* __restrict__ Kh,
    const u16* __restrict__ VT, u16* __restrict__ Op,
    float2* __restrict__ ml) {
  __shared__ __align__(16) u16 Kbuf[4096];       // 64 rows x 128B, swizzled
  __shared__ __align__(16) u16 Vbuf[4096];       // 64 d-rows x 128B, swizzled
  __shared__ __align__(16) uint32_t Pl[8 * 576]; // per-wave 16 rows x 36 dw

  const int tid = threadIdx.x;
  const int wv = tid >> 6, l = tid & 63;
  const int q = l & 15, g = l >> 4;
  const int qt = blockIdx.x, bh = blockIdx.y, z = blockIdx.z;

  const u16* Qp = Qh + ((size_t)bh * 2048 + qt * 128 + wv * 16) * 64;
  const u16* Kp = Kh + (size_t)bh * 2048 * 64;
  const u16* Vp = VT + (size_t)bh * 64 * 2048;

  // Q fragments (B-operand): lane holds Q[q=l&15][d = ks*32 + g*8 .. +7]
  bf16x8 qf[2];
  qf[0] = *(const bf16x8*)(Qp + q * 64 + g * 8);
  qf[1] = *(const bf16x8*)(Qp + q * 64 + 32 + g * 8);

  f32x4 o[4];
#pragma unroll
  for (int df = 0; df < 4; ++df) o[df] = (f32x4){0.f, 0.f, 0.f, 0.f};
  float m = -1e30f, ls = 0.f;

  // staging: wave wv stages rows wv*8..wv*8+7 of each 64x64 tile (1KB/wave)
  const int srow = l >> 3;                       // 0..7 within wave's 8 rows
  const int scolq = (l & 7) ^ srow;              // inverse-swizzled 16B chunk
  const int pbase = wv * 576 + q * 36;
  const char* kb = (const char*)&Kbuf[0];
  const char* vb = (const char*)&Vbuf[0];
  const int rsw = (q & 7) << 4;                  // read swizzle (byte)

#ifdef USE_GLLDS
#define STAGE(t)                                                              \
  do {                                                                        \
    const int n0_ = (t) * 64;                                                 \
    const u16* kg_ = Kp + (size_t)(n0_ + wv * 8 + srow) * 64 + scolq * 8;     \
    const u16* vg_ = Vp + (size_t)(wv * 8 + srow) * 2048 + n0_ + scolq * 8;   \
    async_cp16(kg_, &Kbuf[wv * 512]);                                         \
    async_cp16(vg_, &Vbuf[wv * 512]);                                         \
  } while (0)
#else
#define STAGE(t)                                                              \
  do {                                                                        \
    const int n0_ = (t) * 64;                                                 \
    const u16* kg_ = Kp + (size_t)(n0_ + wv * 8 + srow) * 64 + scolq * 8;     \
    const u16* vg_ = Vp + (size_t)(wv * 8 + srow) * 2048 + n0_ + scolq * 8;   \
    short8 kt_ = *(const short8*)kg_;                                         \
    short8 vt_ = *(const short8*)vg_;                                         \
    *(short8*)&Kbuf[wv * 512 + l * 8] = kt_;                                  \
    *(short8*)&Vbuf[wv * 512 + l * 8] = vt_;                                  \
  } while (0)
#endif

  const int t0 = z * 16;
  for (int tt = 0; tt < 16; ++tt) {
    STAGE(t0 + tt);
    __syncthreads();

    // ---- S' = K . Q'  -> s[nj] holds k = nj*16 + 4g + r, for q = l&15
    f32x4 s[4];
#pragma unroll
    for (int nj = 0; nj < 4; ++nj) s[nj] = (f32x4){0.f, 0.f, 0.f, 0.f};
#pragma unroll
    for (int ks = 0; ks < 2; ++ks) {
#pragma unroll
      for (int nj = 0; nj < 4; ++nj) {
        bf16x8 kf = *(const bf16x8*)(kb + (nj * 16 + q) * 128 +
                                     (((ks * 4 + g) << 4) ^ rsw));
        s[nj] = mfma16(kf, qf[ks], s[nj]);
      }
    }

    // ---- online softmax (exp2 domain), row q over lanes {l,l^16,l^32,l^48}
    const float a0 = fmaxf(fmaxf(s[0][0], s[0][1]), fmaxf(s[0][2], s[0][3]));
    const float a1 = fmaxf(fmaxf(s[1][0], s[1][1]), fmaxf(s[1][2], s[1][3]));
    const float a2 = fmaxf(fmaxf(s[2][0], s[2][1]), fmaxf(s[2][2], s[2][3]));
    const float a3 = fmaxf(fmaxf(s[3][0], s[3][1]), fmaxf(s[3][2], s[3][3]));
    float mt = fmaxf(fmaxf(a0, a1), fmaxf(a2, a3));
    mt = fmaxf(mt, __shfl_xor(mt, 16));
    mt = fmaxf(mt, __shfl_xor(mt, 32));
    if (!__all(mt <= m + 8.f)) {               // defer-max: rescale rarely
      const float nm = fmaxf(m, mt);
      const float rf = fexp2(m - nm);
      m = nm;
      ls *= rf;
#pragma unroll
      for (int df = 0; df < 4; ++df) o[df] *= rf;
    }
    float ps = 0.f;
#pragma unroll
    for (int nj = 0; nj < 4; ++nj)
#pragma unroll
      for (int r = 0; r < 4; ++r) {
        s[nj][r] = fexp2(s[nj][r] - m);
        ps += s[nj][r];
      }
    ps += __shfl_xor(ps, 16);
    ps += __shfl_xor(ps, 32);
    ls += ps;

    // ---- P -> LDS (packed bf16 pairs), per-wave slab, same-wave reuse
#pragma unroll
    for (int nj = 0; nj < 4; ++nj)
#pragma unroll
      for (int pp = 0; pp < 2; ++pp) {
        uint32_t w = (uint32_t)f2bf(s[nj][2 * pp]) |
                     ((uint32_t)f2bf(s[nj][2 * pp + 1]) << 16);
        Pl[pbase + nj * 8 + g * 2 + pp] = w;
      }

    // ---- O^T += V^T . P : lane q = l&15, d = df*16 + 4g + r
#pragma unroll
    for (int ks = 0; ks < 2; ++ks) {
      u32x4 pw = *(const u32x4*)&Pl[pbase + ks * 16 + 4 * g];
      bf16x8 pf = __builtin_bit_cast(bf16x8, pw);
#pragma unroll
      for (int df = 0; df < 4; ++df) {
        bf16x8 vf = *(const bf16x8*)(vb + (df * 16 + q) * 128 +
                                     (((ks * 4 + g) << 4) ^ rsw));
        o[df] = mfma16(vf, pf, o[df]);
      }
    }
    __syncthreads();
  }

  // ---- epilogue: write NORMALIZED partial O (bf16) + (m, ls) per row
  const float inv = 1.f / ls;
  const int rowb = qt * 128 + wv * 16 + q;
  const size_t prow = (size_t)(z * 32 + bh) * 2048 + rowb;
  u16* Po = Op + (prow << 6);
#pragma unroll
  for (int df = 0; df < 4; ++df)
#pragma unroll
    for (int pp = 0; pp < 2; ++pp) {
      uint32_t w = (uint32_t)f2bf(o[df][2 * pp] * inv) |
                   ((uint32_t)f2bf(o[df][2 * pp + 1] * inv) << 16);
      *(uint32_t*)(Po + df * 16 + 4 * g + 2 * pp) = w;
    }
  if (g == 0) ml[prow] = make_float2(m, ls);
}

// ---------------------------------------------------------------------------
// Combine the two KV-half partials: O = (w1*O1n + w2*O2n), w_i ~ ls_i*2^m_i.
// One thread per u32 (2 bf16). Writes merged AO [B,S,H*64].
// ---------------------------------------------------------------------------
__global__ __launch_bounds__(256) void combine(
    const uint32_t* __restrict__ Op32, const float2* __restrict__ ml,
    u16* __restrict__ AO) {
  const int j = blockIdx.x * 256 + threadIdx.x;   // [0, 2M)
  const int rowid = j >> 5, w5 = j & 31;
  const float2 a = ml[rowid];
  const float2 c = ml[(1 << 16) + rowid];
  const float M = fmaxf(a.x, c.x);
  float w1 = a.y * fexp2(a.x - M);
  float w2 = c.y * fexp2(c.x - M);
  const float inv = 1.f / (w1 + w2);
  w1 *= inv;
  w2 *= inv;
  const uint32_t p1 = Op32[j];
  const uint32_t p2 = Op32[(1u << 21) + j];
  const float lo = w1 * __builtin_bit_cast(float, p1 << 16) +
                   w2 * __builtin_bit_cast(float, p2 << 16);
  const float hi = w1 * __builtin_bit_cast(float, p1 & 0xffff0000u) +
                   w2 * __builtin_bit_cast(float, p2 & 0xffff0000u);
  const uint32_t outw = (uint32_t)f2bf(lo) | ((uint32_t)f2bf(hi) << 16);
  const int bh = rowid >> 11, s = rowid & 2047, b = bh >> 4, h = bh & 15;
  ((uint32_t*)AO)[((size_t)(b * 2048 + s) << 9) + h * 32 + w5] = outw;
}

// ---------------------------------------------------------------------------
extern "C" void kernel_launch(void* const* d_in, const int* in_sizes, int n_in,
                              void* d_out, int out_size, void* d_ws,
                              size_t ws_size, hipStream_t stream) {
  const float* q = (const float*)d_in[0];
  const float* k = (const float*)d_in[1];
  const float* v = (const float*)d_in[2];
  const float* w_q = (const float*)d_in[3];
  const float* b_q = (const float*)d_in[4];
  const float* w_k = (const float*)d_in[5];
  const float* b_k = (const float*)d_in[6];
  const float* w_v = (const float*)d_in[7];
  const float* b_v = (const float*)d_in[8];
  const float* w_o = (const float*)d_in[9];
  const float* b_o = (const float*)d_in[10];

  // ws layout (u16 elems): [0,12M) q/k/v bf16 (DEAD after gemm_proj; reused
  // as flash partials), [12M,16M) weights bf16, [16M,20M) Qh, [20M,24M) Kh,
  // [24M,28M) V^T, [28M,32M) attn out. 64 MB total.
  u16* ws = (u16*)d_ws;
  u16* qb = ws;                       // + z*4M for k,v
  u16* wqb = ws + (12u << 20);        // + z*1M for wk,wv
  u16* wob = ws + (15u << 20);
  u16* Qh = ws + (16u << 20);         // z=0 (pre-scaled by 0.125*log2e)
  u16* Kh = ws + (20u << 20);         // z=1
  u16* VT = ws + (24u << 20);         // z=2 (transposed)
  u16* AO = ws + (28u << 20);
  // flash partials overlay the dead q/k/v region:
  u16* Op = ws;                            // bytes [0,16MB): 2 x 4M bf16
  float2* ml = (float2*)(ws + (8u << 20)); // bytes [16,17MB): 128K float2

  cvt_all<<<dim3(8192), dim3(256), 0, stream>>>(q, k, v, w_q, w_k, w_v, w_o, ws);
  gemm_proj<<<dim3(8, 32, 3), dim3(256), 0, stream>>>(qb, wqb, b_q, b_k, b_v, Qh);
  flash_attn3<<<dim3(16, 32, 2), dim3(512), 0, stream>>>(Qh, Kh, VT, Op, ml);
  combine<<<dim3(8192), dim3(256), 0, stream>>>((const uint32_t*)Op, ml, AO);
  gemm_out<<<dim3(8, 32), dim3(256), 0, stream>>>(AO, wob, b_o, (float*)d_out);
}

// Round 8
// 172.168 us; speedup vs baseline: 1.0103x; 1.0103x over previous
//
#include <hip/hip_runtime.h>
#include <hip/hip_bf16.h>
#include <stdint.h>

// Problem constants: B=2, S=2048, D_MODEL=1024, H=16, Dk=64. M = B*S = 4096.
typedef unsigned short u16;
typedef __attribute__((ext_vector_type(8))) short short8;
typedef __attribute__((ext_vector_type(8))) __bf16 bf16x8;
typedef __attribute__((ext_vector_type(4))) float f32x4;
typedef __attribute__((ext_vector_type(4))) uint32_t u32x4;

#if defined(__has_builtin)
#if __has_builtin(__builtin_amdgcn_global_load_lds)
#define USE_GLLDS 1
#endif
#endif

// Fast 2^x: v_exp_f32 is the native HW op. (__exp2f collides with glibc.)
#if defined(__has_builtin)
#if __has_builtin(__builtin_amdgcn_exp2f)
#define HAVE_EXP2_BUILTIN 1
#endif
#endif
__device__ __forceinline__ float fexp2(float x) {
#ifdef HAVE_EXP2_BUILTIN
  return __builtin_amdgcn_exp2f(x);
#else
  return exp2f(x);
#endif
}

__device__ __forceinline__ u16 f2bf(float f) {
  __hip_bfloat16 h = __float2bfloat16(f);
  return __builtin_bit_cast(u16, h);
}

__device__ __forceinline__ f32x4 mfma16(bf16x8 a, bf16x8 b, f32x4 c) {
  return __builtin_amdgcn_mfma_f32_16x16x32_bf16(a, b, c, 0, 0, 0);
}

#ifdef USE_GLLDS
__device__ __forceinline__ void async_cp16(const void* g, void* l) {
  __builtin_amdgcn_global_load_lds(
      (const __attribute__((address_space(1))) void*)g,
      (__attribute__((address_space(3))) void*)l, 16, 0, 0);
}
#endif

// ---------------------------------------------------------------------------
// Kernel 1: fp32 -> bf16 conversion of q,k,v (4M each) and w_q,w_k,w_v,w_o (1M
// each) into one contiguous 16M-element bf16 region at the start of d_ws.
// ---------------------------------------------------------------------------
__global__ __launch_bounds__(256) void cvt_all(
    const float* __restrict__ q, const float* __restrict__ k,
    const float* __restrict__ v, const float* __restrict__ w0,
    const float* __restrict__ w1, const float* __restrict__ w2,
    const float* __restrict__ w3, u16* __restrict__ dst) {
  size_t i = ((size_t)blockIdx.x * 256 + threadIdx.x) * 8;
  const size_t M1 = 1u << 20;
  const float* s;
  size_t base;
  if (i < 4 * M1) { s = q; base = 0; }
  else if (i < 8 * M1) { s = k; base = 4 * M1; }
  else if (i < 12 * M1) { s = v; base = 8 * M1; }
  else if (i < 13 * M1) { s = w0; base = 12 * M1; }
  else if (i < 14 * M1) { s = w1; base = 13 * M1; }
  else if (i < 15 * M1) { s = w2; base = 14 * M1; }
  else { s = w3; base = 15 * M1; }
  const float4 a = *(const float4*)(s + (i - base));
  const float4 b = *(const float4*)(s + (i - base) + 4);
  short8 r;
  r[0] = (short)f2bf(a.x); r[1] = (short)f2bf(a.y);
  r[2] = (short)f2bf(a.z); r[3] = (short)f2bf(a.w);
  r[4] = (short)f2bf(b.x); r[5] = (short)f2bf(b.y);
  r[6] = (short)f2bf(b.z); r[7] = (short)f2bf(b.w);
  *(short8*)(dst + i) = r;
}

// ---------------------------------------------------------------------------
// GEMM: C[M=4096, N=1024] = X[4096,1024] * W[1024,1024]^T + bias.
// 128x128 tile, BK=64, 4 waves. Epilogue modes:
//   0: Q  -> bf16 split-head [B,H,S,64], scaled by 0.125*log2(e)  (exp2 dom.)
//   1: K  -> bf16 split-head [B,H,S,64]
//   2: V  -> bf16 TRANSPOSED split-head [B,H,64,S]  (V^T for the PV mfma)
//   3: fp32 row-major [4096,1024] (output projection)
// ---------------------------------------------------------------------------
__device__ __forceinline__ void gemm_body(const u16* __restrict__ X,
                                          const u16* __restrict__ W,
                                          const float* __restrict__ bias,
                                          void* __restrict__ outp, int mode) {
  __shared__ u16 Al[128 * 64];
  __shared__ u16 Bl[128 * 64];
  const int tid = threadIdx.x;
  const int wv = tid >> 6, l = tid & 63;
  const int wr = wv >> 1, wc = wv & 1;
  const int m0 = blockIdx.y * 128, n0 = blockIdx.x * 128;
  const int lrow = l & 15, lk = (l >> 4) * 8;

  f32x4 acc[4][4];
#pragma unroll
  for (int i = 0; i < 4; ++i)
#pragma unroll
    for (int j = 0; j < 4; ++j) acc[i][j] = (f32x4){0.f, 0.f, 0.f, 0.f};

  const u16* Asrc = X + (size_t)(m0 + (tid >> 3)) * 1024 + (tid & 7) * 8;
  const u16* Bsrc = W + (size_t)(n0 + (tid >> 3)) * 1024 + (tid & 7) * 8;

  for (int kt = 0; kt < 1024; kt += 64) {
#ifdef USE_GLLDS
#pragma unroll
    for (int p = 0; p < 4; ++p) {
      async_cp16(Asrc + (size_t)p * 32 * 1024 + kt, &Al[p * 2048 + wv * 512]);
      async_cp16(Bsrc + (size_t)p * 32 * 1024 + kt, &Bl[p * 2048 + wv * 512]);
    }
#else
    short8 ar[4], br[4];
#pragma unroll
    for (int p = 0; p < 4; ++p) {
      ar[p] = *(const short8*)(Asrc + (size_t)p * 32 * 1024 + kt);
      br[p] = *(const short8*)(Bsrc + (size_t)p * 32 * 1024 + kt);
    }
#pragma unroll
    for (int p = 0; p < 4; ++p) {
      *(short8*)&Al[p * 2048 + tid * 8] = ar[p];
      *(short8*)&Bl[p * 2048 + tid * 8] = br[p];
    }
#endif
    __syncthreads();
#pragma unroll
    for (int ks = 0; ks < 2; ++ks) {
      bf16x8 af[4], bf[4];
#pragma unroll
      for (int mf = 0; mf < 4; ++mf)
        af[mf] = *(const bf16x8*)&Al[(wr * 64 + mf * 16 + lrow) * 64 + ks * 32 + lk];
#pragma unroll
      for (int nf = 0; nf < 4; ++nf)
        bf[nf] = *(const bf16x8*)&Bl[(wc * 64 + nf * 16 + lrow) * 64 + ks * 32 + lk];
#pragma unroll
      for (int mf = 0; mf < 4; ++mf)
#pragma unroll
        for (int nf = 0; nf < 4; ++nf)
          acc[mf][nf] = mfma16(af[mf], bf[nf], acc[mf][nf]);
    }
    __syncthreads();
  }

  const int rb = (l >> 4) * 4;
#pragma unroll
  for (int mf = 0; mf < 4; ++mf) {
#pragma unroll
    for (int nf = 0; nf < 4; ++nf) {
      const int gn = n0 + wc * 64 + nf * 16 + lrow;
      const float bi = bias[gn];
#pragma unroll
      for (int r = 0; r < 4; ++r) {
        const int gm = m0 + wr * 64 + mf * 16 + rb + r;
        float val = acc[mf][nf][r] + bi;
        const int b = gm >> 11, s = gm & 2047, h = gn >> 6, d = gn & 63;
        if (mode == 3) {
          ((float*)outp)[(size_t)gm * 1024 + gn] = val;
        } else if (mode == 2) {
          // V^T: [B,H,64,S]
          ((u16*)outp)[(((size_t)((b * 16 + h) * 64 + d)) << 11) + s] = f2bf(val);
        } else {
          if (mode == 0) val *= 0.18033688f;  // (1/8)*log2(e): exp2-domain
          ((u16*)outp)[(((size_t)((b * 16 + h) * 2048 + s)) << 6) + d] = f2bf(val);
        }
      }
    }
  }
}

__global__ __launch_bounds__(256) void gemm_proj(
    const u16* __restrict__ qb, const u16* __restrict__ wqb,
    const float* __restrict__ b_q, const float* __restrict__ b_k,
    const float* __restrict__ b_v, u16* __restrict__ Qh) {
  const int z = blockIdx.z;
  const float* bias = (z == 0) ? b_q : ((z == 1) ? b_k : b_v);
  gemm_body(qb + ((size_t)z << 22), wqb + ((size_t)z << 20), bias,
            Qh + ((size_t)z << 22), z);
}

__global__ __launch_bounds__(256) void gemm_out(
    const u16* __restrict__ X, const u16* __restrict__ W,
    const float* __restrict__ bias, float* __restrict__ out) {
  gemm_body(X, W, bias, out, 3);
}

// ---------------------------------------------------------------------------
// Flash attention v4: v3 + T14 async-STAGE split + XCD-aware block swizzle.
//   S' = mfma(A=K, B=Q*scale*log2e) -> D[k][q], lane holds q = l&15
//   softmax in exp2 domain, defer-max (THR=8 log2-units)
//   O^T = mfma(A=V^T, B=P) -> D[d][q]
// Grid (16, 32, 2) remapped so each XCD gets a contiguous 128-block chunk
// (8 bh's K/V halves = 2 MB, L2-resident). Block = 8 waves x 16 q-rows.
// K/V: SINGLE LDS buffer (34KB -> 4 blocks/CU) but REG-staged prefetch:
//   iter: {issue next-tile global loads to regs | compute current from LDS |
//          barrier | write regs->LDS | barrier}
// so HBM/L2 latency hides under the ~600-cycle compute phase (T14).
// Writes NORMALIZED bf16 partial O + (m, ls) per row; combine() merges.
// ---------------------------------------------------------------------------
__global__ __launch_bounds__(512, 4) void flash_attn4(
    const u16* __restrict__ Qh, const u16* __restrict__ Kh,
    const u16* __restrict__ VT, u16* __restrict__ Op,
    float2* __restrict__ ml) {
  __shared__ __align__(16) u16 Kbuf[4096];       // 64 rows x 128B, swizzled
  __shared__ __align__(16) u16 Vbuf[4096];       // 64 d-rows x 128B, swizzled
  __shared__ __align__(16) uint32_t Pl[8 * 576]; // per-wave 16 rows x 36 dw

  const int tid = threadIdx.x;
  const int wv = tid >> 6, l = tid & 63;
  const int q = l & 15, g = l >> 4;

  // XCD swizzle: dispatch slot s -> original block o = (s%8)*128 + s/8.
  // XCD x then runs o in [x*128,(x+1)*128): all qt for an 8-bh (or z) group.
  const int s_lin = blockIdx.x + (blockIdx.y << 4) + (blockIdx.z << 9);
  const int o = ((s_lin & 7) << 7) + (s_lin >> 3);
  const int qt = o & 15, bh = (o >> 4) & 31, z = o >> 9;

  const u16* Qp = Qh + ((size_t)bh * 2048 + qt * 128 + wv * 16) * 64;
  const u16* Kp = Kh + (size_t)bh * 2048 * 64;
  const u16* Vp = VT + (size_t)bh * 64 * 2048;

  // Q fragments (B-operand): lane holds Q[q=l&15][d = ks*32 + g*8 .. +7]
  bf16x8 qf[2];
  qf[0] = *(const bf16x8*)(Qp + q * 64 + g * 8);
  qf[1] = *(const bf16x8*)(Qp + q * 64 + 32 + g * 8);

  f32x4 o_acc[4];
#pragma unroll
  for (int df = 0; df < 4; ++df) o_acc[df] = (f32x4){0.f, 0.f, 0.f, 0.f};
  float m = -1e30f, ls = 0.f;

  // staging: wave wv stages rows wv*8..wv*8+7 of each 64x64 tile (1KB/wave)
  const int srow = l >> 3;                       // 0..7 within wave's 8 rows
  const int scolq = (l & 7) ^ srow;              // inverse-swizzled 16B chunk
  const int pbase = wv * 576 + q * 36;
  const char* kb = (const char*)&Kbuf[0];
  const char* vb = (const char*)&Vbuf[0];
  const int rsw = (q & 7) << 4;                  // read swizzle (byte)

  // per-thread global staging pointers; advance per tile
  const u16* kg = Kp + (size_t)(z * 1024 + wv * 8 + srow) * 64 + scolq * 8;
  const u16* vg = Vp + (size_t)(wv * 8 + srow) * 2048 + z * 1024 + scolq * 8;

  // prologue: stage tile 0 through regs
  {
    short8 k0 = *(const short8*)kg;
    short8 v0 = *(const short8*)vg;
    *(short8*)&Kbuf[wv * 512 + l * 8] = k0;
    *(short8*)&Vbuf[wv * 512 + l * 8] = v0;
  }
  kg += 64 * 64;
  vg += 64;
  __syncthreads();

  for (int tt = 0; tt < 16; ++tt) {
    // ---- T14 issue-early: next tile's loads go in flight NOW; they drain
    // at the barrier after this tile's compute (latency hidden).
    short8 kr, vr;
    if (tt < 15) {
      kr = *(const short8*)kg;
      vr = *(const short8*)vg;
      kg += 64 * 64;
      vg += 64;
    }

    // ---- S' = K . Q'  -> s[nj] holds k = nj*16 + 4g + r, for q = l&15
    f32x4 s[4];
#pragma unroll
    for (int nj = 0; nj < 4; ++nj) s[nj] = (f32x4){0.f, 0.f, 0.f, 0.f};
#pragma unroll
    for (int ks = 0; ks < 2; ++ks) {
#pragma unroll
      for (int nj = 0; nj < 4; ++nj) {
        bf16x8 kf = *(const bf16x8*)(kb + (nj * 16 + q) * 128 +
                                     (((ks * 4 + g) << 4) ^ rsw));
        s[nj] = mfma16(kf, qf[ks], s[nj]);
      }
    }

    // ---- online softmax (exp2 domain), row q over lanes {l,l^16,l^32,l^48}
    const float a0 = fmaxf(fmaxf(s[0][0], s[0][1]), fmaxf(s[0][2], s[0][3]));
    const float a1 = fmaxf(fmaxf(s[1][0], s[1][1]), fmaxf(s[1][2], s[1][3]));
    const float a2 = fmaxf(fmaxf(s[2][0], s[2][1]), fmaxf(s[2][2], s[2][3]));
    const float a3 = fmaxf(fmaxf(s[3][0], s[3][1]), fmaxf(s[3][2], s[3][3]));
    float mt = fmaxf(fmaxf(a0, a1), fmaxf(a2, a3));
    mt = fmaxf(mt, __shfl_xor(mt, 16));
    mt = fmaxf(mt, __shfl_xor(mt, 32));
    if (!__all(mt <= m + 8.f)) {               // defer-max: rescale rarely
      const float nm = fmaxf(m, mt);
      const float rf = fexp2(m - nm);
      m = nm;
      ls *= rf;
#pragma unroll
      for (int df = 0; df < 4; ++df) o_acc[df] *= rf;
    }
    float ps = 0.f;
#pragma unroll
    for (int nj = 0; nj < 4; ++nj)
#pragma unroll
      for (int r = 0; r < 4; ++r) {
        s[nj][r] = fexp2(s[nj][r] - m);
        ps += s[nj][r];
      }
    ps += __shfl_xor(ps, 16);
    ps += __shfl_xor(ps, 32);
    ls += ps;

    // ---- P -> LDS (packed bf16 pairs), per-wave slab, same-wave reuse
#pragma unroll
    for (int nj = 0; nj < 4; ++nj)
#pragma unroll
      for (int pp = 0; pp < 2; ++pp) {
        uint32_t w = (uint32_t)f2bf(s[nj][2 * pp]) |
                     ((uint32_t)f2bf(s[nj][2 * pp + 1]) << 16);
        Pl[pbase + nj * 8 + g * 2 + pp] = w;
      }

    // ---- O^T += V^T . P : lane q = l&15, d = df*16 + 4g + r
#pragma unroll
    for (int ks = 0; ks < 2; ++ks) {
      u32x4 pw = *(const u32x4*)&Pl[pbase + ks * 16 + 4 * g];
      bf16x8 pf = __builtin_bit_cast(bf16x8, pw);
#pragma unroll
      for (int df = 0; df < 4; ++df) {
        bf16x8 vf = *(const bf16x8*)(vb + (df * 16 + q) * 128 +
                                     (((ks * 4 + g) << 4) ^ rsw));
        o_acc[df] = mfma16(vf, pf, o_acc[df]);
      }
    }

    // ---- T14 write-late: all waves done reading K/V LDS, then overwrite
    __syncthreads();
    if (tt < 15) {
      *(short8*)&Kbuf[wv * 512 + l * 8] = kr;
      *(short8*)&Vbuf[wv * 512 + l * 8] = vr;
    }
    __syncthreads();
  }

  // ---- epilogue: write NORMALIZED partial O (bf16) + (m, ls) per row
  const float inv = 1.f / ls;
  const int rowb = qt * 128 + wv * 16 + q;
  const size_t prow = (size_t)(z * 32 + bh) * 2048 + rowb;
  u16* Po = Op + (prow << 6);
#pragma unroll
  for (int df = 0; df < 4; ++df)
#pragma unroll
    for (int pp = 0; pp < 2; ++pp) {
      uint32_t w = (uint32_t)f2bf(o_acc[df][2 * pp] * inv) |
                   ((uint32_t)f2bf(o_acc[df][2 * pp + 1] * inv) << 16);
      *(uint32_t*)(Po + df * 16 + 4 * g + 2 * pp) = w;
    }
  if (g == 0) ml[prow] = make_float2(m, ls);
}

// ---------------------------------------------------------------------------
// Combine the two KV-half partials: O = (w1*O1n + w2*O2n), w_i ~ ls_i*2^m_i.
// One thread per u32 (2 bf16). Writes merged AO [B,S,H*64].
// ---------------------------------------------------------------------------
__global__ __launch_bounds__(256) void combine(
    const uint32_t* __restrict__ Op32, const float2* __restrict__ ml,
    u16* __restrict__ AO) {
  const int j = blockIdx.x * 256 + threadIdx.x;   // [0, 2M)
  const int rowid = j >> 5, w5 = j & 31;
  const float2 a = ml[rowid];
  const float2 c = ml[(1 << 16) + rowid];
  const float M = fmaxf(a.x, c.x);
  float w1 = a.y * fexp2(a.x - M);
  float w2 = c.y * fexp2(c.x - M);
  const float inv = 1.f / (w1 + w2);
  w1 *= inv;
  w2 *= inv;
  const uint32_t p1 = Op32[j];
  const uint32_t p2 = Op32[(1u << 21) + j];
  const float lo = w1 * __builtin_bit_cast(float, p1 << 16) +
                   w2 * __builtin_bit_cast(float, p2 << 16);
  const float hi = w1 * __builtin_bit_cast(float, p1 & 0xffff0000u) +
                   w2 * __builtin_bit_cast(float, p2 & 0xffff0000u);
  const uint32_t outw = (uint32_t)f2bf(lo) | ((uint32_t)f2bf(hi) << 16);
  const int bh = rowid >> 11, s = rowid & 2047, b = bh >> 4, h = bh & 15;
  ((uint32_t*)AO)[((size_t)(b * 2048 + s) << 9) + h * 32 + w5] = outw;
}

// ---------------------------------------------------------------------------
extern "C" void kernel_launch(void* const* d_in, const int* in_sizes, int n_in,
                              void* d_out, int out_size, void* d_ws,
                              size_t ws_size, hipStream_t stream) {
  const float* q = (const float*)d_in[0];
  const float* k = (const float*)d_in[1];
  const float* v = (const float*)d_in[2];
  const float* w_q = (const float*)d_in[3];
  const float* b_q = (const float*)d_in[4];
  const float* w_k = (const float*)d_in[5];
  const float* b_k = (const float*)d_in[6];
  const float* w_v = (const float*)d_in[7];
  const float* b_v = (const float*)d_in[8];
  const float* w_o = (const float*)d_in[9];
  const float* b_o = (const float*)d_in[10];

  // ws layout (u16 elems): [0,12M) q/k/v bf16 (DEAD after gemm_proj; reused
  // as flash partials), [12M,16M) weights bf16, [16M,20M) Qh, [20M,24M) Kh,
  // [24M,28M) V^T, [28M,32M) attn out. 64 MB total.
  u16* ws = (u16*)d_ws;
  u16* qb = ws;                       // + z*4M for k,v
  u16* wqb = ws + (12u << 20);        // + z*1M for wk,wv
  u16* wob = ws + (15u << 20);
  u16* Qh = ws + (16u << 20);         // z=0 (pre-scaled by 0.125*log2e)
  u16* Kh = ws + (20u << 20);         // z=1
  u16* VT = ws + (24u << 20);         // z=2 (transposed)
  u16* AO = ws + (28u << 20);
  // flash partials overlay the dead q/k/v region:
  u16* Op = ws;                            // bytes [0,16MB): 2 x 4M bf16
  float2* ml = (float2*)(ws + (8u << 20)); // bytes [16,17MB): 128K float2

  cvt_all<<<dim3(8192), dim3(256), 0, stream>>>(q, k, v, w_q, w_k, w_v, w_o, ws);
  gemm_proj<<<dim3(8, 32, 3), dim3(256), 0, stream>>>(qb, wqb, b_q, b_k, b_v, Qh);
  flash_attn4<<<dim3(16, 32, 2), dim3(512), 0, stream>>>(Qh, Kh, VT, Op, ml);
  combine<<<dim3(8192), dim3(256), 0, stream>>>((const uint32_t*)Op, ml, AO);
  gemm_out<<<dim3(8, 32), dim3(256), 0, stream>>>(AO, wob, b_o, (float*)d_out);
}

// Round 9
// 164.799 us; speedup vs baseline: 1.0554x; 1.0447x over previous
//
#include <hip/hip_runtime.h>
#include <hip/hip_bf16.h>
#include <stdint.h>

// Problem constants: B=2, S=2048, D_MODEL=1024, H=16, Dk=64. M = B*S = 4096.
typedef unsigned short u16;
typedef __attribute__((ext_vector_type(8))) short short8;
typedef __attribute__((ext_vector_type(8))) __bf16 bf16x8;
typedef __attribute__((ext_vector_type(4))) float f32x4;
typedef __attribute__((ext_vector_type(4))) uint32_t u32x4;

#if defined(__has_builtin)
#if __has_builtin(__builtin_amdgcn_global_load_lds)
#define USE_GLLDS 1
#endif
#endif

// Fast 2^x: v_exp_f32 is the native HW op. (__exp2f collides with glibc.)
#if defined(__has_builtin)
#if __has_builtin(__builtin_amdgcn_exp2f)
#define HAVE_EXP2_BUILTIN 1
#endif
#endif
__device__ __forceinline__ float fexp2(float x) {
#ifdef HAVE_EXP2_BUILTIN
  return __builtin_amdgcn_exp2f(x);
#else
  return exp2f(x);
#endif
}

__device__ __forceinline__ u16 f2bf(float f) {
  __hip_bfloat16 h = __float2bfloat16(f);
  return __builtin_bit_cast(u16, h);
}

__device__ __forceinline__ f32x4 mfma16(bf16x8 a, bf16x8 b, f32x4 c) {
  return __builtin_amdgcn_mfma_f32_16x16x32_bf16(a, b, c, 0, 0, 0);
}

#ifdef USE_GLLDS
__device__ __forceinline__ void async_cp16(const void* g, void* l) {
  __builtin_amdgcn_global_load_lds(
      (const __attribute__((address_space(1))) void*)g,
      (__attribute__((address_space(3))) void*)l, 16, 0, 0);
}
#endif

// ---------------------------------------------------------------------------
// Kernel 1: fp32 -> bf16 conversion of q,k,v (4M each) and w_q,w_k,w_v,w_o (1M
// each) into one contiguous 16M-element bf16 region at the start of d_ws.
// ---------------------------------------------------------------------------
__global__ __launch_bounds__(256) void cvt_all(
    const float* __restrict__ q, const float* __restrict__ k,
    const float* __restrict__ v, const float* __restrict__ w0,
    const float* __restrict__ w1, const float* __restrict__ w2,
    const float* __restrict__ w3, u16* __restrict__ dst) {
  size_t i = ((size_t)blockIdx.x * 256 + threadIdx.x) * 8;
  const size_t M1 = 1u << 20;
  const float* s;
  size_t base;
  if (i < 4 * M1) { s = q; base = 0; }
  else if (i < 8 * M1) { s = k; base = 4 * M1; }
  else if (i < 12 * M1) { s = v; base = 8 * M1; }
  else if (i < 13 * M1) { s = w0; base = 12 * M1; }
  else if (i < 14 * M1) { s = w1; base = 13 * M1; }
  else if (i < 15 * M1) { s = w2; base = 14 * M1; }
  else { s = w3; base = 15 * M1; }
  const float4 a = *(const float4*)(s + (i - base));
  const float4 b = *(const float4*)(s + (i - base) + 4);
  short8 r;
  r[0] = (short)f2bf(a.x); r[1] = (short)f2bf(a.y);
  r[2] = (short)f2bf(a.z); r[3] = (short)f2bf(a.w);
  r[4] = (short)f2bf(b.x); r[5] = (short)f2bf(b.y);
  r[6] = (short)f2bf(b.z); r[7] = (short)f2bf(b.w);
  *(short8*)(dst + i) = r;
}

// ---------------------------------------------------------------------------
// GEMM core: C[128x128 tile] = X[4096,1024] * W^T + bias, 2-PHASE PIPELINED.
// Double-buffered LDS (64 KB); STAGE(next) issued BEFORE compute(cur) so the
// global_load_lds latency hides under the MFMA phase; ONE barrier per K-step.
// Epilogue modes:
//   0: Q  -> bf16 split-head [B,H,S,64], scaled by 0.125*log2(e)  (exp2 dom.)
//   1: K  -> bf16 split-head [B,H,S,64]
//   2: V  -> bf16 TRANSPOSED split-head [B,H,64,S]  (V^T for the PV mfma)
//   3: fp32 row-major [4096,1024] (output projection)
// W passed PRE-OFFSET to the tile's first output row; n0 = local col base.
// ---------------------------------------------------------------------------
__device__ __forceinline__ void gemm_core(const u16* __restrict__ X,
                                          const u16* __restrict__ W,
                                          const float* __restrict__ bias,
                                          void* __restrict__ outp, int mode,
                                          int m0, int n0) {
  __shared__ u16 Al[2][128 * 64];
  __shared__ u16 Bl[2][128 * 64];
  const int tid = threadIdx.x;
  const int wv = tid >> 6, l = tid & 63;
  const int wr = wv >> 1, wc = wv & 1;
  const int lrow = l & 15, lk = (l >> 4) * 8;

  f32x4 acc[4][4];
#pragma unroll
  for (int i = 0; i < 4; ++i)
#pragma unroll
    for (int j = 0; j < 4; ++j) acc[i][j] = (f32x4){0.f, 0.f, 0.f, 0.f};

  const u16* Asrc = X + (size_t)(m0 + (tid >> 3)) * 1024 + (tid & 7) * 8;
  const u16* Bsrc = W + (size_t)(tid >> 3) * 1024 + (tid & 7) * 8;

#ifdef USE_GLLDS
#define GSTAGE(buf, kt)                                                       \
  do {                                                                        \
    _Pragma("unroll")                                                         \
    for (int p = 0; p < 4; ++p) {                                             \
      async_cp16(Asrc + (size_t)p * 32 * 1024 + (kt),                         \
                 &Al[buf][p * 2048 + wv * 512]);                              \
      async_cp16(Bsrc + (size_t)p * 32 * 1024 + (kt),                         \
                 &Bl[buf][p * 2048 + wv * 512]);                              \
    }                                                                         \
  } while (0)
#else
#define GSTAGE(buf, kt)                                                       \
  do {                                                                        \
    short8 ar_[4], br_[4];                                                    \
    _Pragma("unroll")                                                         \
    for (int p = 0; p < 4; ++p) {                                             \
      ar_[p] = *(const short8*)(Asrc + (size_t)p * 32 * 1024 + (kt));         \
      br_[p] = *(const short8*)(Bsrc + (size_t)p * 32 * 1024 + (kt));         \
    }                                                                         \
    _Pragma("unroll")                                                         \
    for (int p = 0; p < 4; ++p) {                                             \
      *(short8*)&Al[buf][p * 2048 + tid * 8] = ar_[p];                        \
      *(short8*)&Bl[buf][p * 2048 + tid * 8] = br_[p];                        \
    }                                                                         \
  } while (0)
#endif

  GSTAGE(0, 0);
  __syncthreads();

  for (int kt = 0; kt < 1024; kt += 64) {
    const int cur = (kt >> 6) & 1;
    if (kt < 1024 - 64) GSTAGE(cur ^ 1, kt + 64);  // issue-early (T3 2-phase)
#pragma unroll
    for (int ks = 0; ks < 2; ++ks) {
      bf16x8 af[4], bf[4];
#pragma unroll
      for (int mf = 0; mf < 4; ++mf)
        af[mf] = *(const bf16x8*)&Al[cur][(wr * 64 + mf * 16 + lrow) * 64 +
                                         ks * 32 + lk];
#pragma unroll
      for (int nf = 0; nf < 4; ++nf)
        bf[nf] = *(const bf16x8*)&Bl[cur][(wc * 64 + nf * 16 + lrow) * 64 +
                                          ks * 32 + lk];
#pragma unroll
      for (int mf = 0; mf < 4; ++mf)
#pragma unroll
        for (int nf = 0; nf < 4; ++nf)
          acc[mf][nf] = mfma16(af[mf], bf[nf], acc[mf][nf]);
    }
    // one barrier per K-step: drains the prefetch (ready for next iter) and
    // protects buf[cur] from being overwritten before all waves read it.
    __syncthreads();
  }
#undef GSTAGE

  const int rb = (l >> 4) * 4;
#pragma unroll
  for (int mf = 0; mf < 4; ++mf) {
#pragma unroll
    for (int nf = 0; nf < 4; ++nf) {
      const int gn = n0 + wc * 64 + nf * 16 + lrow;
      const float bi = bias[gn];
#pragma unroll
      for (int r = 0; r < 4; ++r) {
        const int gm = m0 + wr * 64 + mf * 16 + rb + r;
        float val = acc[mf][nf][r] + bi;
        const int b = gm >> 11, s = gm & 2047, h = gn >> 6, d = gn & 63;
        if (mode == 3) {
          ((float*)outp)[(size_t)gm * 1024 + gn] = val;
        } else if (mode == 2) {
          // V^T: [B,H,64,S]
          ((u16*)outp)[(((size_t)((b * 16 + h) * 64 + d)) << 11) + s] = f2bf(val);
        } else {
          if (mode == 0) val *= 0.18033688f;  // (1/8)*log2(e): exp2-domain
          ((u16*)outp)[(((size_t)((b * 16 + h) * 2048 + s)) << 6) + d] = f2bf(val);
        }
      }
    }
  }
}

// gemm_proj: one fused grid over the concatenated-N view (N = 3072 = 3x1024).
// 768 blocks; XCD-chunk swizzle: slot s -> xcd=s&7 (round-robin dispatch), so
// XCD chunk = 96 blocks covering (12 nx x 8 my); within-chunk my-strips of 12
// nx. Per-XCD L2 working set: B-panel 3MB + streaming A-tiles ~0.5MB < 4MB.
__global__ __launch_bounds__(256, 2) void gemm_proj(
    const u16* __restrict__ qb, const u16* __restrict__ wqb,
    const float* __restrict__ b_q, const float* __restrict__ b_k,
    const float* __restrict__ b_v, u16* __restrict__ Qh) {
  const int s = blockIdx.x;
  const int xcd = s & 7, c = s >> 3;              // c in [0,96)
  const int nx = (xcd >> 2) * 12 + (c % 12);      // [0,24)
  const int my = (xcd & 3) * 8 + (c / 12);        // [0,32)
  const int z = nx >> 3, nxl = nx & 7;
  const float* bias = (z == 0) ? b_q : ((z == 1) ? b_k : b_v);
  gemm_core(qb + ((size_t)z << 22), wqb + ((size_t)nx << 17), bias,
            Qh + ((size_t)z << 22), z, my * 128, nxl * 128);
}

// gemm_out: 256 blocks; chunk = 32 blocks covering (4 nx x 8 my).
__global__ __launch_bounds__(256, 2) void gemm_out(
    const u16* __restrict__ X, const u16* __restrict__ W,
    const float* __restrict__ bias, float* __restrict__ out) {
  const int s = blockIdx.x;
  const int xcd = s & 7, c = s >> 3;              // c in [0,32)
  const int nx = (xcd >> 2) * 4 + (c & 3);        // [0,8)
  const int my = (xcd & 3) * 8 + (c >> 2);        // [0,32)
  gemm_core(X, W + ((size_t)nx << 17), bias, out, 3, my * 128, nx * 128);
}

// ---------------------------------------------------------------------------
// Flash attention v4: swapped-operand + split-KV(2) + T14 reg prefetch + XCD
// swizzle. (Unchanged from round 8.)
// ---------------------------------------------------------------------------
__global__ __launch_bounds__(512, 4) void flash_attn4(
    const u16* __restrict__ Qh, const u16* __restrict__ Kh,
    const u16* __restrict__ VT, u16* __restrict__ Op,
    float2* __restrict__ ml) {
  __shared__ __align__(16) u16 Kbuf[4096];       // 64 rows x 128B, swizzled
  __shared__ __align__(16) u16 Vbuf[4096];       // 64 d-rows x 128B, swizzled
  __shared__ __align__(16) uint32_t Pl[8 * 576]; // per-wave 16 rows x 36 dw

  const int tid = threadIdx.x;
  const int wv = tid >> 6, l = tid & 63;
  const int q = l & 15, g = l >> 4;

  // XCD swizzle: dispatch slot s -> original block o = (s%8)*128 + s/8.
  const int s_lin = blockIdx.x + (blockIdx.y << 4) + (blockIdx.z << 9);
  const int o = ((s_lin & 7) << 7) + (s_lin >> 3);
  const int qt = o & 15, bh = (o >> 4) & 31, z = o >> 9;

  const u16* Qp = Qh + ((size_t)bh * 2048 + qt * 128 + wv * 16) * 64;
  const u16* Kp = Kh + (size_t)bh * 2048 * 64;
  const u16* Vp = VT + (size_t)bh * 64 * 2048;

  // Q fragments (B-operand): lane holds Q[q=l&15][d = ks*32 + g*8 .. +7]
  bf16x8 qf[2];
  qf[0] = *(const bf16x8*)(Qp + q * 64 + g * 8);
  qf[1] = *(const bf16x8*)(Qp + q * 64 + 32 + g * 8);

  f32x4 o_acc[4];
#pragma unroll
  for (int df = 0; df < 4; ++df) o_acc[df] = (f32x4){0.f, 0.f, 0.f, 0.f};
  float m = -1e30f, ls = 0.f;

  // staging: wave wv stages rows wv*8..wv*8+7 of each 64x64 tile (1KB/wave)
  const int srow = l >> 3;                       // 0..7 within wave's 8 rows
  const int scolq = (l & 7) ^ srow;              // inverse-swizzled 16B chunk
  const int pbase = wv * 576 + q * 36;
  const char* kb = (const char*)&Kbuf[0];
  const char* vb = (const char*)&Vbuf[0];
  const int rsw = (q & 7) << 4;                  // read swizzle (byte)

  // per-thread global staging pointers; advance per tile
  const u16* kg = Kp + (size_t)(z * 1024 + wv * 8 + srow) * 64 + scolq * 8;
  const u16* vg = Vp + (size_t)(wv * 8 + srow) * 2048 + z * 1024 + scolq * 8;

  // prologue: stage tile 0 through regs
  {
    short8 k0 = *(const short8*)kg;
    short8 v0 = *(const short8*)vg;
    *(short8*)&Kbuf[wv * 512 + l * 8] = k0;
    *(short8*)&Vbuf[wv * 512 + l * 8] = v0;
  }
  kg += 64 * 64;
  vg += 64;
  __syncthreads();

  for (int tt = 0; tt < 16; ++tt) {
    // ---- T14 issue-early: next tile's loads go in flight NOW
    short8 kr, vr;
    if (tt < 15) {
      kr = *(const short8*)kg;
      vr = *(const short8*)vg;
      kg += 64 * 64;
      vg += 64;
    }

    // ---- S' = K . Q'  -> s[nj] holds k = nj*16 + 4g + r, for q = l&15
    f32x4 s[4];
#pragma unroll
    for (int nj = 0; nj < 4; ++nj) s[nj] = (f32x4){0.f, 0.f, 0.f, 0.f};
#pragma unroll
    for (int ks = 0; ks < 2; ++ks) {
#pragma unroll
      for (int nj = 0; nj < 4; ++nj) {
        bf16x8 kf = *(const bf16x8*)(kb + (nj * 16 + q) * 128 +
                                     (((ks * 4 + g) << 4) ^ rsw));
        s[nj] = mfma16(kf, qf[ks], s[nj]);
      }
    }

    // ---- online softmax (exp2 domain), row q over lanes {l,l^16,l^32,l^48}
    const float a0 = fmaxf(fmaxf(s[0][0], s[0][1]), fmaxf(s[0][2], s[0][3]));
    const float a1 = fmaxf(fmaxf(s[1][0], s[1][1]), fmaxf(s[1][2], s[1][3]));
    const float a2 = fmaxf(fmaxf(s[2][0], s[2][1]), fmaxf(s[2][2], s[2][3]));
    const float a3 = fmaxf(fmaxf(s[3][0], s[3][1]), fmaxf(s[3][2], s[3][3]));
    float mt = fmaxf(fmaxf(a0, a1), fmaxf(a2, a3));
    mt = fmaxf(mt, __shfl_xor(mt, 16));
    mt = fmaxf(mt, __shfl_xor(mt, 32));
    if (!__all(mt <= m + 8.f)) {               // defer-max: rescale rarely
      const float nm = fmaxf(m, mt);
      const float rf = fexp2(m - nm);
      m = nm;
      ls *= rf;
#pragma unroll
      for (int df = 0; df < 4; ++df) o_acc[df] *= rf;
    }
    float ps = 0.f;
#pragma unroll
    for (int nj = 0; nj < 4; ++nj)
#pragma unroll
      for (int r = 0; r < 4; ++r) {
        s[nj][r] = fexp2(s[nj][r] - m);
        ps += s[nj][r];
      }
    ps += __shfl_xor(ps, 16);
    ps += __shfl_xor(ps, 32);
    ls += ps;

    // ---- P -> LDS (packed bf16 pairs), per-wave slab, same-wave reuse
#pragma unroll
    for (int nj = 0; nj < 4; ++nj)
#pragma unroll
      for (int pp = 0; pp < 2; ++pp) {
        uint32_t w = (uint32_t)f2bf(s[nj][2 * pp]) |
                     ((uint32_t)f2bf(s[nj][2 * pp + 1]) << 16);
        Pl[pbase + nj * 8 + g * 2 + pp] = w;
      }

    // ---- O^T += V^T . P : lane q = l&15, d = df*16 + 4g + r
#pragma unroll
    for (int ks = 0; ks < 2; ++ks) {
      u32x4 pw = *(const u32x4*)&Pl[pbase + ks * 16 + 4 * g];
      bf16x8 pf = __builtin_bit_cast(bf16x8, pw);
#pragma unroll
      for (int df = 0; df < 4; ++df) {
        bf16x8 vf = *(const bf16x8*)(vb + (df * 16 + q) * 128 +
                                     (((ks * 4 + g) << 4) ^ rsw));
        o_acc[df] = mfma16(vf, pf, o_acc[df]);
      }
    }

    // ---- T14 write-late: all waves done reading K/V LDS, then overwrite
    __syncthreads();
    if (tt < 15) {
      *(short8*)&Kbuf[wv * 512 + l * 8] = kr;
      *(short8*)&Vbuf[wv * 512 + l * 8] = vr;
    }
    __syncthreads();
  }

  // ---- epilogue: write NORMALIZED partial O (bf16) + (m, ls) per row
  const float inv = 1.f / ls;
  const int rowb = qt * 128 + wv * 16 + q;
  const size_t prow = (size_t)(z * 32 + bh) * 2048 + rowb;
  u16* Po = Op + (prow << 6);
#pragma unroll
  for (int df = 0; df < 4; ++df)
#pragma unroll
    for (int pp = 0; pp < 2; ++pp) {
      uint32_t w = (uint32_t)f2bf(o_acc[df][2 * pp] * inv) |
                   ((uint32_t)f2bf(o_acc[df][2 * pp + 1] * inv) << 16);
      *(uint32_t*)(Po + df * 16 + 4 * g + 2 * pp) = w;
    }
  if (g == 0) ml[prow] = make_float2(m, ls);
}

// ---------------------------------------------------------------------------
// Combine the two KV-half partials: O = (w1*O1n + w2*O2n), w_i ~ ls_i*2^m_i.
// ---------------------------------------------------------------------------
__global__ __launch_bounds__(256) void combine(
    const uint32_t* __restrict__ Op32, const float2* __restrict__ ml,
    u16* __restrict__ AO) {
  const int j = blockIdx.x * 256 + threadIdx.x;   // [0, 2M)
  const int rowid = j >> 5, w5 = j & 31;
  const float2 a = ml[rowid];
  const float2 c = ml[(1 << 16) + rowid];
  const float M = fmaxf(a.x, c.x);
  float w1 = a.y * fexp2(a.x - M);
  float w2 = c.y * fexp2(c.x - M);
  const float inv = 1.f / (w1 + w2);
  w1 *= inv;
  w2 *= inv;
  const uint32_t p1 = Op32[j];
  const uint32_t p2 = Op32[(1u << 21) + j];
  const float lo = w1 * __builtin_bit_cast(float, p1 << 16) +
                   w2 * __builtin_bit_cast(float, p2 << 16);
  const float hi = w1 * __builtin_bit_cast(float, p1 & 0xffff0000u) +
                   w2 * __builtin_bit_cast(float, p2 & 0xffff0000u);
  const uint32_t outw = (uint32_t)f2bf(lo) | ((uint32_t)f2bf(hi) << 16);
  const int bh = rowid >> 11, s = rowid & 2047, b = bh >> 4, h = bh & 15;
  ((uint32_t*)AO)[((size_t)(b * 2048 + s) << 9) + h * 32 + w5] = outw;
}

// ---------------------------------------------------------------------------
extern "C" void kernel_launch(void* const* d_in, const int* in_sizes, int n_in,
                              void* d_out, int out_size, void* d_ws,
                              size_t ws_size, hipStream_t stream) {
  const float* q = (const float*)d_in[0];
  const float* k = (const float*)d_in[1];
  const float* v = (const float*)d_in[2];
  const float* w_q = (const float*)d_in[3];
  const float* b_q = (const float*)d_in[4];
  const float* w_k = (const float*)d_in[5];
  const float* b_k = (const float*)d_in[6];
  const float* w_v = (const float*)d_in[7];
  const float* b_v = (const float*)d_in[8];
  const float* w_o = (const float*)d_in[9];
  const float* b_o = (const float*)d_in[10];

  // ws layout (u16 elems): [0,12M) q/k/v bf16 (DEAD after gemm_proj; reused
  // as flash partials), [12M,16M) weights bf16, [16M,20M) Qh, [20M,24M) Kh,
  // [24M,28M) V^T, [28M,32M) attn out. 64 MB total.
  u16* ws = (u16*)d_ws;
  u16* qb = ws;                       // + z*4M for k,v
  u16* wqb = ws + (12u << 20);        // + z*1M for wk,wv (contiguous concat)
  u16* wob = ws + (15u << 20);
  u16* Qh = ws + (16u << 20);         // z=0 (pre-scaled by 0.125*log2e)
  u16* Kh = ws + (20u << 20);         // z=1
  u16* VT = ws + (24u << 20);         // z=2 (transposed)
  u16* AO = ws + (28u << 20);
  // flash partials overlay the dead q/k/v region:
  u16* Op = ws;                            // bytes [0,16MB): 2 x 4M bf16
  float2* ml = (float2*)(ws + (8u << 20)); // bytes [16,17MB): 128K float2

  cvt_all<<<dim3(8192), dim3(256), 0, stream>>>(q, k, v, w_q, w_k, w_v, w_o, ws);
  gemm_proj<<<dim3(768), dim3(256), 0, stream>>>(qb, wqb, b_q, b_k, b_v, Qh);
  flash_attn4<<<dim3(16, 32, 2), dim3(512), 0, stream>>>(Qh, Kh, VT, Op, ml);
  combine<<<dim3(8192), dim3(256), 0, stream>>>((const uint32_t*)Op, ml, AO);
  gemm_out<<<dim3(256), dim3(256), 0, stream>>>(AO, wob, b_o, (float*)d_out);
}

// Round 10
// 163.721 us; speedup vs baseline: 1.0624x; 1.0066x over previous
//
#include <hip/hip_runtime.h>
#include <hip/hip_bf16.h>
#include <stdint.h>

// Problem constants: B=2, S=2048, D_MODEL=1024, H=16, Dk=64. M = B*S = 4096.
typedef unsigned short u16;
typedef __attribute__((ext_vector_type(8))) short short8;
typedef __attribute__((ext_vector_type(8))) __bf16 bf16x8;
typedef __attribute__((ext_vector_type(4))) float f32x4;
typedef __attribute__((ext_vector_type(4))) uint32_t u32x4;

#if defined(__has_builtin)
#if __has_builtin(__builtin_amdgcn_global_load_lds)
#define USE_GLLDS 1
#endif
#endif

// Fast 2^x: v_exp_f32 is the native HW op. (__exp2f collides with glibc.)
#if defined(__has_builtin)
#if __has_builtin(__builtin_amdgcn_exp2f)
#define HAVE_EXP2_BUILTIN 1
#endif
#endif
__device__ __forceinline__ float fexp2(float x) {
#ifdef HAVE_EXP2_BUILTIN
  return __builtin_amdgcn_exp2f(x);
#else
  return exp2f(x);
#endif
}

__device__ __forceinline__ u16 f2bf(float f) {
  __hip_bfloat16 h = __float2bfloat16(f);
  return __builtin_bit_cast(u16, h);
}

__device__ __forceinline__ f32x4 mfma16(bf16x8 a, bf16x8 b, f32x4 c) {
  return __builtin_amdgcn_mfma_f32_16x16x32_bf16(a, b, c, 0, 0, 0);
}

#ifdef USE_GLLDS
__device__ __forceinline__ void async_cp16(const void* g, void* l) {
  __builtin_amdgcn_global_load_lds(
      (const __attribute__((address_space(1))) void*)g,
      (__attribute__((address_space(3))) void*)l, 16, 0, 0);
}
#endif

// ---------------------------------------------------------------------------
// Kernel 1: fp32 -> bf16 conversion of q,k,v (4M each) and w_q,w_k,w_v,w_o (1M
// each) into one contiguous 16M-element bf16 region at the start of d_ws.
// ---------------------------------------------------------------------------
__global__ __launch_bounds__(256) void cvt_all(
    const float* __restrict__ q, const float* __restrict__ k,
    const float* __restrict__ v, const float* __restrict__ w0,
    const float* __restrict__ w1, const float* __restrict__ w2,
    const float* __restrict__ w3, u16* __restrict__ dst) {
  size_t i = ((size_t)blockIdx.x * 256 + threadIdx.x) * 8;
  const size_t M1 = 1u << 20;
  const float* s;
  size_t base;
  if (i < 4 * M1) { s = q; base = 0; }
  else if (i < 8 * M1) { s = k; base = 4 * M1; }
  else if (i < 12 * M1) { s = v; base = 8 * M1; }
  else if (i < 13 * M1) { s = w0; base = 12 * M1; }
  else if (i < 14 * M1) { s = w1; base = 13 * M1; }
  else if (i < 15 * M1) { s = w2; base = 14 * M1; }
  else { s = w3; base = 15 * M1; }
  const float4 a = *(const float4*)(s + (i - base));
  const float4 b = *(const float4*)(s + (i - base) + 4);
  short8 r;
  r[0] = (short)f2bf(a.x); r[1] = (short)f2bf(a.y);
  r[2] = (short)f2bf(a.z); r[3] = (short)f2bf(a.w);
  r[4] = (short)f2bf(b.x); r[5] = (short)f2bf(b.y);
  r[6] = (short)f2bf(b.z); r[7] = (short)f2bf(b.w);
  *(short8*)(dst + i) = r;
}

// ---------------------------------------------------------------------------
// GEMM core v2: 8 waves (512 threads), 128x128 tile, BK=64, SINGLE 32KB LDS
// buffer (m97 2-barrier structure). Wave tile = 64x32 (acc 4x2 -> 32 VGPR),
// so 3 blocks/CU = 24 waves/CU of TLP hides the staging latency (the round-9
// 64KB dbuf cut occupancy to 2 blocks/CU and was latency-exposed).
// Epilogue modes:
//   0: Q  -> bf16 split-head [B,H,S,64], scaled by 0.125*log2(e)  (exp2 dom.)
//   1: K  -> bf16 split-head [B,H,S,64]
//   2: V  -> bf16 TRANSPOSED split-head [B,H,64,S]  (V^T for the PV mfma)
//   3: fp32 row-major [4096,1024] (output projection)
// W passed PRE-OFFSET to the tile's first output row; n0 = local col base.
// ---------------------------------------------------------------------------
__device__ __forceinline__ void gemm_core8(const u16* __restrict__ X,
                                           const u16* __restrict__ W,
                                           const float* __restrict__ bias,
                                           void* __restrict__ outp, int mode,
                                           int m0, int n0) {
  __shared__ u16 Al[128 * 64];
  __shared__ u16 Bl[128 * 64];
  const int tid = threadIdx.x;
  const int wv = tid >> 6, l = tid & 63;
  const int wr = wv >> 2, wc = wv & 3;       // wave tile: rows wr*64, cols wc*32
  const int lrow = l & 15, lk = (l >> 4) * 8;

  f32x4 acc[4][2];
#pragma unroll
  for (int i = 0; i < 4; ++i)
#pragma unroll
    for (int j = 0; j < 2; ++j) acc[i][j] = (f32x4){0.f, 0.f, 0.f, 0.f};

  // staging: wave wv stages rows {wv*8..wv*8+7} and {+64} of each 128x64 tile
  const int srow = l >> 3;            // 0..7
  const int scol = (l & 7) * 8;       // 0..56
  const u16* Asrc = X + (size_t)(m0 + wv * 8 + srow) * 1024 + scol;
  const u16* Bsrc = W + (size_t)(wv * 8 + srow) * 1024 + scol;

  for (int kt = 0; kt < 1024; kt += 64) {
#ifdef USE_GLLDS
    async_cp16(Asrc + kt, &Al[(wv * 8) * 64]);
    async_cp16(Asrc + (size_t)64 * 1024 + kt, &Al[(wv * 8 + 64) * 64]);
    async_cp16(Bsrc + kt, &Bl[(wv * 8) * 64]);
    async_cp16(Bsrc + (size_t)64 * 1024 + kt, &Bl[(wv * 8 + 64) * 64]);
#else
    short8 a0 = *(const short8*)(Asrc + kt);
    short8 a1 = *(const short8*)(Asrc + (size_t)64 * 1024 + kt);
    short8 b0 = *(const short8*)(Bsrc + kt);
    short8 b1 = *(const short8*)(Bsrc + (size_t)64 * 1024 + kt);
    *(short8*)&Al[(wv * 8 + srow) * 64 + scol] = a0;
    *(short8*)&Al[(wv * 8 + 64 + srow) * 64 + scol] = a1;
    *(short8*)&Bl[(wv * 8 + srow) * 64 + scol] = b0;
    *(short8*)&Bl[(wv * 8 + 64 + srow) * 64 + scol] = b1;
#endif
    __syncthreads();   // drains staging (compiler inserts vmcnt/lgkm wait)
#pragma unroll
    for (int ks = 0; ks < 2; ++ks) {
      bf16x8 af[4], bf[2];
#pragma unroll
      for (int mf = 0; mf < 4; ++mf)
        af[mf] = *(const bf16x8*)&Al[(wr * 64 + mf * 16 + lrow) * 64 +
                                     ks * 32 + lk];
#pragma unroll
      for (int nf = 0; nf < 2; ++nf)
        bf[nf] = *(const bf16x8*)&Bl[(wc * 32 + nf * 16 + lrow) * 64 +
                                     ks * 32 + lk];
#pragma unroll
      for (int mf = 0; mf < 4; ++mf)
#pragma unroll
        for (int nf = 0; nf < 2; ++nf)
          acc[mf][nf] = mfma16(af[mf], bf[nf], acc[mf][nf]);
    }
    __syncthreads();   // protect buffer before next stage overwrites
  }

  const int rb = (l >> 4) * 4;
#pragma unroll
  for (int mf = 0; mf < 4; ++mf) {
#pragma unroll
    for (int nf = 0; nf < 2; ++nf) {
      const int gn = n0 + wc * 32 + nf * 16 + lrow;
      const float bi = bias[gn];
#pragma unroll
      for (int r = 0; r < 4; ++r) {
        const int gm = m0 + wr * 64 + mf * 16 + rb + r;
        float val = acc[mf][nf][r] + bi;
        const int b = gm >> 11, s = gm & 2047, h = gn >> 6, d = gn & 63;
        if (mode == 3) {
          ((float*)outp)[(size_t)gm * 1024 + gn] = val;
        } else if (mode == 2) {
          // V^T: [B,H,64,S]
          ((u16*)outp)[(((size_t)((b * 16 + h) * 64 + d)) << 11) + s] = f2bf(val);
        } else {
          if (mode == 0) val *= 0.18033688f;  // (1/8)*log2(e): exp2-domain
          ((u16*)outp)[(((size_t)((b * 16 + h) * 2048 + s)) << 6) + d] = f2bf(val);
        }
      }
    }
  }
}

// gemm_proj: fused grid over concatenated-N (N = 3072). 768 blocks; XCD-chunk
// swizzle (slot s -> xcd=s&7): chunk = 96 blocks (12 nx x 8 my); per-XCD L2
// working set ~3.5MB < 4MB (proven: FETCH 101->42MB in round 9).
__global__ __launch_bounds__(512, 6) void gemm_proj(
    const u16* __restrict__ qb, const u16* __restrict__ wqb,
    const float* __restrict__ b_q, const float* __restrict__ b_k,
    const float* __restrict__ b_v, u16* __restrict__ Qh) {
  const int s = blockIdx.x;
  const int xcd = s & 7, c = s >> 3;              // c in [0,96)
  const int nx = (xcd >> 2) * 12 + (c % 12);      // [0,24)
  const int my = (xcd & 3) * 8 + (c / 12);        // [0,32)
  const int z = nx >> 3, nxl = nx & 7;
  const float* bias = (z == 0) ? b_q : ((z == 1) ? b_k : b_v);
  gemm_core8(qb + ((size_t)z << 22), wqb + ((size_t)nx << 17), bias,
             Qh + ((size_t)z << 22), z, my * 128, nxl * 128);
}

// gemm_out: 256 blocks; chunk = 32 blocks (4 nx x 8 my).
__global__ __launch_bounds__(512, 6) void gemm_out(
    const u16* __restrict__ X, const u16* __restrict__ W,
    const float* __restrict__ bias, float* __restrict__ out) {
  const int s = blockIdx.x;
  const int xcd = s & 7, c = s >> 3;              // c in [0,32)
  const int nx = (xcd >> 2) * 4 + (c & 3);        // [0,8)
  const int my = (xcd & 3) * 8 + (c >> 2);        // [0,32)
  gemm_core8(X, W + ((size_t)nx << 17), bias, out, 3, my * 128, nx * 128);
}

// ---------------------------------------------------------------------------
// Flash attention v4: swapped-operand + split-KV(2) + T14 reg prefetch + XCD
// swizzle. (Unchanged from round 8/9.)
// ---------------------------------------------------------------------------
__global__ __launch_bounds__(512, 4) void flash_attn4(
    const u16* __restrict__ Qh, const u16* __restrict__ Kh,
    const u16* __restrict__ VT, u16* __restrict__ Op,
    float2* __restrict__ ml) {
  __shared__ __align__(16) u16 Kbuf[4096];       // 64 rows x 128B, swizzled
  __shared__ __align__(16) u16 Vbuf[4096];       // 64 d-rows x 128B, swizzled
  __shared__ __align__(16) uint32_t Pl[8 * 576]; // per-wave 16 rows x 36 dw

  const int tid = threadIdx.x;
  const int wv = tid >> 6, l = tid & 63;
  const int q = l & 15, g = l >> 4;

  // XCD swizzle: dispatch slot s -> original block o = (s%8)*128 + s/8.
  const int s_lin = blockIdx.x + (blockIdx.y << 4) + (blockIdx.z << 9);
  const int o = ((s_lin & 7) << 7) + (s_lin >> 3);
  const int qt = o & 15, bh = (o >> 4) & 31, z = o >> 9;

  const u16* Qp = Qh + ((size_t)bh * 2048 + qt * 128 + wv * 16) * 64;
  const u16* Kp = Kh + (size_t)bh * 2048 * 64;
  const u16* Vp = VT + (size_t)bh * 64 * 2048;

  // Q fragments (B-operand): lane holds Q[q=l&15][d = ks*32 + g*8 .. +7]
  bf16x8 qf[2];
  qf[0] = *(const bf16x8*)(Qp + q * 64 + g * 8);
  qf[1] = *(const bf16x8*)(Qp + q * 64 + 32 + g * 8);

  f32x4 o_acc[4];
#pragma unroll
  for (int df = 0; df < 4; ++df) o_acc[df] = (f32x4){0.f, 0.f, 0.f, 0.f};
  float m = -1e30f, ls = 0.f;

  // staging: wave wv stages rows wv*8..wv*8+7 of each 64x64 tile (1KB/wave)
  const int srow = l >> 3;                       // 0..7 within wave's 8 rows
  const int scolq = (l & 7) ^ srow;              // inverse-swizzled 16B chunk
  const int pbase = wv * 576 + q * 36;
  const char* kb = (const char*)&Kbuf[0];
  const char* vb = (const char*)&Vbuf[0];
  const int rsw = (q & 7) << 4;                  // read swizzle (byte)

  // per-thread global staging pointers; advance per tile
  const u16* kg = Kp + (size_t)(z * 1024 + wv * 8 + srow) * 64 + scolq * 8;
  const u16* vg = Vp + (size_t)(wv * 8 + srow) * 2048 + z * 1024 + scolq * 8;

  // prologue: stage tile 0 through regs
  {
    short8 k0 = *(const short8*)kg;
    short8 v0 = *(const short8*)vg;
    *(short8*)&Kbuf[wv * 512 + l * 8] = k0;
    *(short8*)&Vbuf[wv * 512 + l * 8] = v0;
  }
  kg += 64 * 64;
  vg += 64;
  __syncthreads();

  for (int tt = 0; tt < 16; ++tt) {
    // ---- T14 issue-early: next tile's loads go in flight NOW
    short8 kr, vr;
    if (tt < 15) {
      kr = *(const short8*)kg;
      vr = *(const short8*)vg;
      kg += 64 * 64;
      vg += 64;
    }

    // ---- S' = K . Q'  -> s[nj] holds k = nj*16 + 4g + r, for q = l&15
    f32x4 s[4];
#pragma unroll
    for (int nj = 0; nj < 4; ++nj) s[nj] = (f32x4){0.f, 0.f, 0.f, 0.f};
#pragma unroll
    for (int ks = 0; ks < 2; ++ks) {
#pragma unroll
      for (int nj = 0; nj < 4; ++nj) {
        bf16x8 kf = *(const bf16x8*)(kb + (nj * 16 + q) * 128 +
                                     (((ks * 4 + g) << 4) ^ rsw));
        s[nj] = mfma16(kf, qf[ks], s[nj]);
      }
    }

    // ---- online softmax (exp2 domain), row q over lanes {l,l^16,l^32,l^48}
    const float a0 = fmaxf(fmaxf(s[0][0], s[0][1]), fmaxf(s[0][2], s[0][3]));
    const float a1 = fmaxf(fmaxf(s[1][0], s[1][1]), fmaxf(s[1][2], s[1][3]));
    const float a2 = fmaxf(fmaxf(s[2][0], s[2][1]), fmaxf(s[2][2], s[2][3]));
    const float a3 = fmaxf(fmaxf(s[3][0], s[3][1]), fmaxf(s[3][2], s[3][3]));
    float mt = fmaxf(fmaxf(a0, a1), fmaxf(a2, a3));
    mt = fmaxf(mt, __shfl_xor(mt, 16));
    mt = fmaxf(mt, __shfl_xor(mt, 32));
    if (!__all(mt <= m + 8.f)) {               // defer-max: rescale rarely
      const float nm = fmaxf(m, mt);
      const float rf = fexp2(m - nm);
      m = nm;
      ls *= rf;
#pragma unroll
      for (int df = 0; df < 4; ++df) o_acc[df] *= rf;
    }
    float ps = 0.f;
#pragma unroll
    for (int nj = 0; nj < 4; ++nj)
#pragma unroll
      for (int r = 0; r < 4; ++r) {
        s[nj][r] = fexp2(s[nj][r] - m);
        ps += s[nj][r];
      }
    ps += __shfl_xor(ps, 16);
    ps += __shfl_xor(ps, 32);
    ls += ps;

    // ---- P -> LDS (packed bf16 pairs), per-wave slab, same-wave reuse
#pragma unroll
    for (int nj = 0; nj < 4; ++nj)
#pragma unroll
      for (int pp = 0; pp < 2; ++pp) {
        uint32_t w = (uint32_t)f2bf(s[nj][2 * pp]) |
                     ((uint32_t)f2bf(s[nj][2 * pp + 1]) << 16);
        Pl[pbase + nj * 8 + g * 2 + pp] = w;
      }

    // ---- O^T += V^T . P : lane q = l&15, d = df*16 + 4g + r
#pragma unroll
    for (int ks = 0; ks < 2; ++ks) {
      u32x4 pw = *(const u32x4*)&Pl[pbase + ks * 16 + 4 * g];
      bf16x8 pf = __builtin_bit_cast(bf16x8, pw);
#pragma unroll
      for (int df = 0; df < 4; ++df) {
        bf16x8 vf = *(const bf16x8*)(vb + (df * 16 + q) * 128 +
                                     (((ks * 4 + g) << 4) ^ rsw));
        o_acc[df] = mfma16(vf, pf, o_acc[df]);
      }
    }

    // ---- T14 write-late: all waves done reading K/V LDS, then overwrite
    __syncthreads();
    if (tt < 15) {
      *(short8*)&Kbuf[wv * 512 + l * 8] = kr;
      *(short8*)&Vbuf[wv * 512 + l * 8] = vr;
    }
    __syncthreads();
  }

  // ---- epilogue: write NORMALIZED partial O (bf16) + (m, ls) per row
  const float inv = 1.f / ls;
  const int rowb = qt * 128 + wv * 16 + q;
  const size_t prow = (size_t)(z * 32 + bh) * 2048 + rowb;
  u16* Po = Op + (prow << 6);
#pragma unroll
  for (int df = 0; df < 4; ++df)
#pragma unroll
    for (int pp = 0; pp < 2; ++pp) {
      uint32_t w = (uint32_t)f2bf(o_acc[df][2 * pp] * inv) |
                   ((uint32_t)f2bf(o_acc[df][2 * pp + 1] * inv) << 16);
      *(uint32_t*)(Po + df * 16 + 4 * g + 2 * pp) = w;
    }
  if (g == 0) ml[prow] = make_float2(m, ls);
}

// ---------------------------------------------------------------------------
// Combine the two KV-half partials: O = (w1*O1n + w2*O2n), w_i ~ ls_i*2^m_i.
// ---------------------------------------------------------------------------
__global__ __launch_bounds__(256) void combine(
    const uint32_t* __restrict__ Op32, const float2* __restrict__ ml,
    u16* __restrict__ AO) {
  const int j = blockIdx.x * 256 + threadIdx.x;   // [0, 2M)
  const int rowid = j >> 5, w5 = j & 31;
  const float2 a = ml[rowid];
  const float2 c = ml[(1 << 16) + rowid];
  const float M = fmaxf(a.x, c.x);
  float w1 = a.y * fexp2(a.x - M);
  float w2 = c.y * fexp2(c.x - M);
  const float inv = 1.f / (w1 + w2);
  w1 *= inv;
  w2 *= inv;
  const uint32_t p1 = Op32[j];
  const uint32_t p2 = Op32[(1u << 21) + j];
  const float lo = w1 * __builtin_bit_cast(float, p1 << 16) +
                   w2 * __builtin_bit_cast(float, p2 << 16);
  const float hi = w1 * __builtin_bit_cast(float, p1 & 0xffff0000u) +
                   w2 * __builtin_bit_cast(float, p2 & 0xffff0000u);
  const uint32_t outw = (uint32_t)f2bf(lo) | ((uint32_t)f2bf(hi) << 16);
  const int bh = rowid >> 11, s = rowid & 2047, b = bh >> 4, h = bh & 15;
  ((uint32_t*)AO)[((size_t)(b * 2048 + s) << 9) + h * 32 + w5] = outw;
}

// ---------------------------------------------------------------------------
extern "C" void kernel_launch(void* const* d_in, const int* in_sizes, int n_in,
                              void* d_out, int out_size, void* d_ws,
                              size_t ws_size, hipStream_t stream) {
  const float* q = (const float*)d_in[0];
  const float* k = (const float*)d_in[1];
  const float* v = (const float*)d_in[2];
  const float* w_q = (const float*)d_in[3];
  const float* b_q = (const float*)d_in[4];
  const float* w_k = (const float*)d_in[5];
  const float* b_k = (const float*)d_in[6];
  const float* w_v = (const float*)d_in[7];
  const float* b_v = (const float*)d_in[8];
  const float* w_o = (const float*)d_in[9];
  const float* b_o = (const float*)d_in[10];

  // ws layout (u16 elems): [0,12M) q/k/v bf16 (DEAD after gemm_proj; reused
  // as flash partials), [12M,16M) weights bf16, [16M,20M) Qh, [20M,24M) Kh,
  // [24M,28M) V^T, [28M,32M) attn out. 64 MB total.
  u16* ws = (u16*)d_ws;
  u16* qb = ws;                       // + z*4M for k,v
  u16* wqb = ws + (12u << 20);        // + z*1M for wk,wv (contiguous concat)
  u16* wob = ws + (15u << 20);
  u16* Qh = ws + (16u << 20);         // z=0 (pre-scaled by 0.125*log2e)
  u16* Kh = ws + (20u << 20);         // z=1
  u16* VT = ws + (24u << 20);         // z=2 (transposed)
  u16* AO = ws + (28u << 20);
  // flash partials overlay the dead q/k/v region:
  u16* Op = ws;                            // bytes [0,16MB): 2 x 4M bf16
  float2* ml = (float2*)(ws + (8u << 20)); // bytes [16,17MB): 128K float2

  cvt_all<<<dim3(8192), dim3(256), 0, stream>>>(q, k, v, w_q, w_k, w_v, w_o, ws);
  gemm_proj<<<dim3(768), dim3(512), 0, stream>>>(qb, wqb, b_q, b_k, b_v, Qh);
  flash_attn4<<<dim3(16, 32, 2), dim3(512), 0, stream>>>(Qh, Kh, VT, Op, ml);
  combine<<<dim3(8192), dim3(256), 0, stream>>>((const uint32_t*)Op, ml, AO);
  gemm_out<<<dim3(256), dim3(512), 0, stream>>>(AO, wob, b_o, (float*)d_out);
}

// Round 11
// 163.041 us; speedup vs baseline: 1.0668x; 1.0042x over previous
//
#include <hip/hip_runtime.h>
#include <hip/hip_bf16.h>
#include <stdint.h>

// Problem constants: B=2, S=2048, D_MODEL=1024, H=16, Dk=64. M = B*S = 4096.
typedef unsigned short u16;
typedef __attribute__((ext_vector_type(8))) short short8;
typedef __attribute__((ext_vector_type(8))) __bf16 bf16x8;
typedef __attribute__((ext_vector_type(4))) float f32x4;
typedef __attribute__((ext_vector_type(4))) uint32_t u32x4;

#if defined(__has_builtin)
#if __has_builtin(__builtin_amdgcn_global_load_lds)
#define USE_GLLDS 1
#endif
#endif

// Fast 2^x: v_exp_f32 is the native HW op. (__exp2f collides with glibc.)
#if defined(__has_builtin)
#if __has_builtin(__builtin_amdgcn_exp2f)
#define HAVE_EXP2_BUILTIN 1
#endif
#endif
__device__ __forceinline__ float fexp2(float x) {
#ifdef HAVE_EXP2_BUILTIN
  return __builtin_amdgcn_exp2f(x);
#else
  return exp2f(x);
#endif
}

__device__ __forceinline__ u16 f2bf(float f) {
  __hip_bfloat16 h = __float2bfloat16(f);
  return __builtin_bit_cast(u16, h);
}

// Pack 2 fp32 -> 1 u32 of 2 bf16 (RNE) in ONE instruction. No builtin on
// gfx950 (m240) -- inline asm per T12 recipe.
__device__ __forceinline__ uint32_t cvt_pk_bf16(float lo, float hi) {
  uint32_t w;
  asm("v_cvt_pk_bf16_f32 %0, %1, %2" : "=v"(w) : "v"(lo), "v"(hi));
  return w;
}

__device__ __forceinline__ f32x4 mfma16(bf16x8 a, bf16x8 b, f32x4 c) {
  return __builtin_amdgcn_mfma_f32_16x16x32_bf16(a, b, c, 0, 0, 0);
}

#ifdef USE_GLLDS
__device__ __forceinline__ void async_cp16(const void* g, void* l) {
  __builtin_amdgcn_global_load_lds(
      (const __attribute__((address_space(1))) void*)g,
      (__attribute__((address_space(3))) void*)l, 16, 0, 0);
}
#endif

// ---------------------------------------------------------------------------
// Kernel 1: fp32 -> bf16 conversion of q,k,v (4M each) and w_q,w_k,w_v,w_o (1M
// each) into one contiguous 16M-element bf16 region at the start of d_ws.
// ---------------------------------------------------------------------------
__global__ __launch_bounds__(256) void cvt_all(
    const float* __restrict__ q, const float* __restrict__ k,
    const float* __restrict__ v, const float* __restrict__ w0,
    const float* __restrict__ w1, const float* __restrict__ w2,
    const float* __restrict__ w3, u16* __restrict__ dst) {
  size_t i = ((size_t)blockIdx.x * 256 + threadIdx.x) * 8;
  const size_t M1 = 1u << 20;
  const float* s;
  size_t base;
  if (i < 4 * M1) { s = q; base = 0; }
  else if (i < 8 * M1) { s = k; base = 4 * M1; }
  else if (i < 12 * M1) { s = v; base = 8 * M1; }
  else if (i < 13 * M1) { s = w0; base = 12 * M1; }
  else if (i < 14 * M1) { s = w1; base = 13 * M1; }
  else if (i < 15 * M1) { s = w2; base = 14 * M1; }
  else { s = w3; base = 15 * M1; }
  const float4 a = *(const float4*)(s + (i - base));
  const float4 b = *(const float4*)(s + (i - base) + 4);
  short8 r;
  r[0] = (short)f2bf(a.x); r[1] = (short)f2bf(a.y);
  r[2] = (short)f2bf(a.z); r[3] = (short)f2bf(a.w);
  r[4] = (short)f2bf(b.x); r[5] = (short)f2bf(b.y);
  r[6] = (short)f2bf(b.z); r[7] = (short)f2bf(b.w);
  *(short8*)(dst + i) = r;
}

// ---------------------------------------------------------------------------
// GEMM core v2: 8 waves (512 threads), 128x128 tile, BK=64, SINGLE 32KB LDS
// buffer (m97 2-barrier structure). Wave tile = 64x32 (acc 4x2 -> 32 VGPR),
// 3 blocks/CU = 24 waves/CU of TLP hides the staging latency.
// Epilogue modes:
//   0: Q  -> bf16 split-head [B,H,S,64], scaled by 0.125*log2(e)  (exp2 dom.)
//   1: K  -> bf16 split-head [B,H,S,64]
//   2: V  -> bf16 TRANSPOSED split-head [B,H,64,S]  (V^T for the PV mfma)
//   3: fp32 row-major [4096,1024] (output projection)
// W passed PRE-OFFSET to the tile's first output row; n0 = local col base.
// ---------------------------------------------------------------------------
__device__ __forceinline__ void gemm_core8(const u16* __restrict__ X,
                                           const u16* __restrict__ W,
                                           const float* __restrict__ bias,
                                           void* __restrict__ outp, int mode,
                                           int m0, int n0) {
  __shared__ u16 Al[128 * 64];
  __shared__ u16 Bl[128 * 64];
  const int tid = threadIdx.x;
  const int wv = tid >> 6, l = tid & 63;
  const int wr = wv >> 2, wc = wv & 3;       // wave tile: rows wr*64, cols wc*32
  const int lrow = l & 15, lk = (l >> 4) * 8;

  f32x4 acc[4][2];
#pragma unroll
  for (int i = 0; i < 4; ++i)
#pragma unroll
    for (int j = 0; j < 2; ++j) acc[i][j] = (f32x4){0.f, 0.f, 0.f, 0.f};

  // staging: wave wv stages rows {wv*8..wv*8+7} and {+64} of each 128x64 tile
  const int srow = l >> 3;            // 0..7
  const int scol = (l & 7) * 8;       // 0..56
  const u16* Asrc = X + (size_t)(m0 + wv * 8 + srow) * 1024 + scol;
  const u16* Bsrc = W + (size_t)(wv * 8 + srow) * 1024 + scol;

  for (int kt = 0; kt < 1024; kt += 64) {
#ifdef USE_GLLDS
    async_cp16(Asrc + kt, &Al[(wv * 8) * 64]);
    async_cp16(Asrc + (size_t)64 * 1024 + kt, &Al[(wv * 8 + 64) * 64]);
    async_cp16(Bsrc + kt, &Bl[(wv * 8) * 64]);
    async_cp16(Bsrc + (size_t)64 * 1024 + kt, &Bl[(wv * 8 + 64) * 64]);
#else
    short8 a0 = *(const short8*)(Asrc + kt);
    short8 a1 = *(const short8*)(Asrc + (size_t)64 * 1024 + kt);
    short8 b0 = *(const short8*)(Bsrc + kt);
    short8 b1 = *(const short8*)(Bsrc + (size_t)64 * 1024 + kt);
    *(short8*)&Al[(wv * 8 + srow) * 64 + scol] = a0;
    *(short8*)&Al[(wv * 8 + 64 + srow) * 64 + scol] = a1;
    *(short8*)&Bl[(wv * 8 + srow) * 64 + scol] = b0;
    *(short8*)&Bl[(wv * 8 + 64 + srow) * 64 + scol] = b1;
#endif
    __syncthreads();   // drains staging (compiler inserts vmcnt/lgkm wait)
#pragma unroll
    for (int ks = 0; ks < 2; ++ks) {
      bf16x8 af[4], bf[2];
#pragma unroll
      for (int mf = 0; mf < 4; ++mf)
        af[mf] = *(const bf16x8*)&Al[(wr * 64 + mf * 16 + lrow) * 64 +
                                     ks * 32 + lk];
#pragma unroll
      for (int nf = 0; nf < 2; ++nf)
        bf[nf] = *(const bf16x8*)&Bl[(wc * 32 + nf * 16 + lrow) * 64 +
                                     ks * 32 + lk];
#pragma unroll
      for (int mf = 0; mf < 4; ++mf)
#pragma unroll
        for (int nf = 0; nf < 2; ++nf)
          acc[mf][nf] = mfma16(af[mf], bf[nf], acc[mf][nf]);
    }
    __syncthreads();   // protect buffer before next stage overwrites
  }

  const int rb = (l >> 4) * 4;
#pragma unroll
  for (int mf = 0; mf < 4; ++mf) {
#pragma unroll
    for (int nf = 0; nf < 2; ++nf) {
      const int gn = n0 + wc * 32 + nf * 16 + lrow;
      const float bi = bias[gn];
#pragma unroll
      for (int r = 0; r < 4; ++r) {
        const int gm = m0 + wr * 64 + mf * 16 + rb + r;
        float val = acc[mf][nf][r] + bi;
        const int b = gm >> 11, s = gm & 2047, h = gn >> 6, d = gn & 63;
        if (mode == 3) {
          ((float*)outp)[(size_t)gm * 1024 + gn] = val;
        } else if (mode == 2) {
          // V^T: [B,H,64,S]
          ((u16*)outp)[(((size_t)((b * 16 + h) * 64 + d)) << 11) + s] = f2bf(val);
        } else {
          if (mode == 0) val *= 0.18033688f;  // (1/8)*log2(e): exp2-domain
          ((u16*)outp)[(((size_t)((b * 16 + h) * 2048 + s)) << 6) + d] = f2bf(val);
        }
      }
    }
  }
}

// gemm_proj: fused grid over concatenated-N (N = 3072). 768 blocks; XCD-chunk
// swizzle (slot s -> xcd=s&7): chunk = 96 blocks (12 nx x 8 my); per-XCD L2
// working set ~3.5MB < 4MB (proven: FETCH 101->42MB in round 9).
__global__ __launch_bounds__(512, 6) void gemm_proj(
    const u16* __restrict__ qb, const u16* __restrict__ wqb,
    const float* __restrict__ b_q, const float* __restrict__ b_k,
    const float* __restrict__ b_v, u16* __restrict__ Qh) {
  const int s = blockIdx.x;
  const int xcd = s & 7, c = s >> 3;              // c in [0,96)
  const int nx = (xcd >> 2) * 12 + (c % 12);      // [0,24)
  const int my = (xcd & 3) * 8 + (c / 12);        // [0,32)
  const int z = nx >> 3, nxl = nx & 7;
  const float* bias = (z == 0) ? b_q : ((z == 1) ? b_k : b_v);
  gemm_core8(qb + ((size_t)z << 22), wqb + ((size_t)nx << 17), bias,
             Qh + ((size_t)z << 22), z, my * 128, nxl * 128);
}

// gemm_out: 256 blocks; chunk = 32 blocks (4 nx x 8 my).
__global__ __launch_bounds__(512, 6) void gemm_out(
    const u16* __restrict__ X, const u16* __restrict__ W,
    const float* __restrict__ bias, float* __restrict__ out) {
  const int s = blockIdx.x;
  const int xcd = s & 7, c = s >> 3;              // c in [0,32)
  const int nx = (xcd >> 2) * 4 + (c & 3);        // [0,8)
  const int my = (xcd & 3) * 8 + (c >> 2);        // [0,32)
  gemm_core8(X, W + ((size_t)nx << 17), bias, out, 3, my * 128, nx * 128);
}

// ---------------------------------------------------------------------------
// Flash attention v5: v4 + v_cvt_pk_bf16_f32 packing (T12 component).
// The P->bf16 pack was 16x __float2bfloat16 (~4 VALU ops each) + 8 ORs per
// tile; cvt_pk does 2 values/instruction -> 8 instructions. Same RNE rounding.
// ---------------------------------------------------------------------------
__global__ __launch_bounds__(512, 4) void flash_attn5(
    const u16* __restrict__ Qh, const u16* __restrict__ Kh,
    const u16* __restrict__ VT, u16* __restrict__ Op,
    float2* __restrict__ ml) {
  __shared__ __align__(16) u16 Kbuf[4096];       // 64 rows x 128B, swizzled
  __shared__ __align__(16) u16 Vbuf[4096];       // 64 d-rows x 128B, swizzled
  __shared__ __align__(16) uint32_t Pl[8 * 576]; // per-wave 16 rows x 36 dw

  const int tid = threadIdx.x;
  const int wv = tid >> 6, l = tid & 63;
  const int q = l & 15, g = l >> 4;

  // XCD swizzle: dispatch slot s -> original block o = (s%8)*128 + s/8.
  const int s_lin = blockIdx.x + (blockIdx.y << 4) + (blockIdx.z << 9);
  const int o = ((s_lin & 7) << 7) + (s_lin >> 3);
  const int qt = o & 15, bh = (o >> 4) & 31, z = o >> 9;

  const u16* Qp = Qh + ((size_t)bh * 2048 + qt * 128 + wv * 16) * 64;
  const u16* Kp = Kh + (size_t)bh * 2048 * 64;
  const u16* Vp = VT + (size_t)bh * 64 * 2048;

  // Q fragments (B-operand): lane holds Q[q=l&15][d = ks*32 + g*8 .. +7]
  bf16x8 qf[2];
  qf[0] = *(const bf16x8*)(Qp + q * 64 + g * 8);
  qf[1] = *(const bf16x8*)(Qp + q * 64 + 32 + g * 8);

  f32x4 o_acc[4];
#pragma unroll
  for (int df = 0; df < 4; ++df) o_acc[df] = (f32x4){0.f, 0.f, 0.f, 0.f};
  float m = -1e30f, ls = 0.f;

  // staging: wave wv stages rows wv*8..wv*8+7 of each 64x64 tile (1KB/wave)
  const int srow = l >> 3;                       // 0..7 within wave's 8 rows
  const int scolq = (l & 7) ^ srow;              // inverse-swizzled 16B chunk
  const int pbase = wv * 576 + q * 36;
  const char* kb = (const char*)&Kbuf[0];
  const char* vb = (const char*)&Vbuf[0];
  const int rsw = (q & 7) << 4;                  // read swizzle (byte)

  // per-thread global staging pointers; advance per tile
  const u16* kg = Kp + (size_t)(z * 1024 + wv * 8 + srow) * 64 + scolq * 8;
  const u16* vg = Vp + (size_t)(wv * 8 + srow) * 2048 + z * 1024 + scolq * 8;

  // prologue: stage tile 0 through regs
  {
    short8 k0 = *(const short8*)kg;
    short8 v0 = *(const short8*)vg;
    *(short8*)&Kbuf[wv * 512 + l * 8] = k0;
    *(short8*)&Vbuf[wv * 512 + l * 8] = v0;
  }
  kg += 64 * 64;
  vg += 64;
  __syncthreads();

  for (int tt = 0; tt < 16; ++tt) {
    // ---- T14 issue-early: next tile's loads go in flight NOW
    short8 kr, vr;
    if (tt < 15) {
      kr = *(const short8*)kg;
      vr = *(const short8*)vg;
      kg += 64 * 64;
      vg += 64;
    }

    // ---- S' = K . Q'  -> s[nj] holds k = nj*16 + 4g + r, for q = l&15
    f32x4 s[4];
#pragma unroll
    for (int nj = 0; nj < 4; ++nj) s[nj] = (f32x4){0.f, 0.f, 0.f, 0.f};
#pragma unroll
    for (int ks = 0; ks < 2; ++ks) {
#pragma unroll
      for (int nj = 0; nj < 4; ++nj) {
        bf16x8 kf = *(const bf16x8*)(kb + (nj * 16 + q) * 128 +
                                     (((ks * 4 + g) << 4) ^ rsw));
        s[nj] = mfma16(kf, qf[ks], s[nj]);
      }
    }

    // ---- online softmax (exp2 domain), row q over lanes {l,l^16,l^32,l^48}
    const float a0 = fmaxf(fmaxf(s[0][0], s[0][1]), fmaxf(s[0][2], s[0][3]));
    const float a1 = fmaxf(fmaxf(s[1][0], s[1][1]), fmaxf(s[1][2], s[1][3]));
    const float a2 = fmaxf(fmaxf(s[2][0], s[2][1]), fmaxf(s[2][2], s[2][3]));
    const float a3 = fmaxf(fmaxf(s[3][0], s[3][1]), fmaxf(s[3][2], s[3][3]));
    float mt = fmaxf(fmaxf(a0, a1), fmaxf(a2, a3));
    mt = fmaxf(mt, __shfl_xor(mt, 16));
    mt = fmaxf(mt, __shfl_xor(mt, 32));
    if (!__all(mt <= m + 8.f)) {               // defer-max: rescale rarely
      const float nm = fmaxf(m, mt);
      const float rf = fexp2(m - nm);
      m = nm;
      ls *= rf;
#pragma unroll
      for (int df = 0; df < 4; ++df) o_acc[df] *= rf;
    }
    float ps = 0.f;
#pragma unroll
    for (int nj = 0; nj < 4; ++nj)
#pragma unroll
      for (int r = 0; r < 4; ++r) {
        s[nj][r] = fexp2(s[nj][r] - m);
        ps += s[nj][r];
      }
    ps += __shfl_xor(ps, 16);
    ps += __shfl_xor(ps, 32);
    ls += ps;

    // ---- P -> LDS via v_cvt_pk_bf16_f32 (1 inst per 2 values; was ~9)
#pragma unroll
    for (int nj = 0; nj < 4; ++nj)
#pragma unroll
      for (int pp = 0; pp < 2; ++pp)
        Pl[pbase + nj * 8 + g * 2 + pp] =
            cvt_pk_bf16(s[nj][2 * pp], s[nj][2 * pp + 1]);

    // ---- O^T += V^T . P : lane q = l&15, d = df*16 + 4g + r
#pragma unroll
    for (int ks = 0; ks < 2; ++ks) {
      u32x4 pw = *(const u32x4*)&Pl[pbase + ks * 16 + 4 * g];
      bf16x8 pf = __builtin_bit_cast(bf16x8, pw);
#pragma unroll
      for (int df = 0; df < 4; ++df) {
        bf16x8 vf = *(const bf16x8*)(vb + (df * 16 + q) * 128 +
                                     (((ks * 4 + g) << 4) ^ rsw));
        o_acc[df] = mfma16(vf, pf, o_acc[df]);
      }
    }

    // ---- T14 write-late: all waves done reading K/V LDS, then overwrite
    __syncthreads();
    if (tt < 15) {
      *(short8*)&Kbuf[wv * 512 + l * 8] = kr;
      *(short8*)&Vbuf[wv * 512 + l * 8] = vr;
    }
    __syncthreads();
  }

  // ---- epilogue: write NORMALIZED partial O (bf16) + (m, ls) per row
  const float inv = 1.f / ls;
  const int rowb = qt * 128 + wv * 16 + q;
  const size_t prow = (size_t)(z * 32 + bh) * 2048 + rowb;
  u16* Po = Op + (prow << 6);
#pragma unroll
  for (int df = 0; df < 4; ++df)
#pragma unroll
    for (int pp = 0; pp < 2; ++pp) {
      uint32_t w = cvt_pk_bf16(o_acc[df][2 * pp] * inv,
                               o_acc[df][2 * pp + 1] * inv);
      *(uint32_t*)(Po + df * 16 + 4 * g + 2 * pp) = w;
    }
  if (g == 0) ml[prow] = make_float2(m, ls);
}

// ---------------------------------------------------------------------------
// Combine the two KV-half partials: O = (w1*O1n + w2*O2n), w_i ~ ls_i*2^m_i.
// ---------------------------------------------------------------------------
__global__ __launch_bounds__(256) void combine(
    const uint32_t* __restrict__ Op32, const float2* __restrict__ ml,
    u16* __restrict__ AO) {
  const int j = blockIdx.x * 256 + threadIdx.x;   // [0, 2M)
  const int rowid = j >> 5, w5 = j & 31;
  const float2 a = ml[rowid];
  const float2 c = ml[(1 << 16) + rowid];
  const float M = fmaxf(a.x, c.x);
  float w1 = a.y * fexp2(a.x - M);
  float w2 = c.y * fexp2(c.x - M);
  const float inv = 1.f / (w1 + w2);
  w1 *= inv;
  w2 *= inv;
  const uint32_t p1 = Op32[j];
  const uint32_t p2 = Op32[(1u << 21) + j];
  const float lo = w1 * __builtin_bit_cast(float, p1 << 16) +
                   w2 * __builtin_bit_cast(float, p2 << 16);
  const float hi = w1 * __builtin_bit_cast(float, p1 & 0xffff0000u) +
                   w2 * __builtin_bit_cast(float, p2 & 0xffff0000u);
  const uint32_t outw = cvt_pk_bf16(lo, hi);
  const int bh = rowid >> 11, s = rowid & 2047, b = bh >> 4, h = bh & 15;
  ((uint32_t*)AO)[((size_t)(b * 2048 + s) << 9) + h * 32 + w5] = outw;
}

// ---------------------------------------------------------------------------
extern "C" void kernel_launch(void* const* d_in, const int* in_sizes, int n_in,
                              void* d_out, int out_size, void* d_ws,
                              size_t ws_size, hipStream_t stream) {
  const float* q = (const float*)d_in[0];
  const float* k = (const float*)d_in[1];
  const float* v = (const float*)d_in[2];
  const float* w_q = (const float*)d_in[3];
  const float* b_q = (const float*)d_in[4];
  const float* w_k = (const float*)d_in[5];
  const float* b_k = (const float*)d_in[6];
  const float* w_v = (const float*)d_in[7];
  const float* b_v = (const float*)d_in[8];
  const float* w_o = (const float*)d_in[9];
  const float* b_o = (const float*)d_in[10];

  // ws layout (u16 elems): [0,12M) q/k/v bf16 (DEAD after gemm_proj; reused
  // as flash partials), [12M,16M) weights bf16, [16M,20M) Qh, [20M,24M) Kh,
  // [24M,28M) V^T, [28M,32M) attn out. 64 MB total.
  u16* ws = (u16*)d_ws;
  u16* qb = ws;                       // + z*4M for k,v
  u16* wqb = ws + (12u << 20);        // + z*1M for wk,wv (contiguous concat)
  u16* wob = ws + (15u << 20);
  u16* Qh = ws + (16u << 20);         // z=0 (pre-scaled by 0.125*log2e)
  u16* Kh = ws + (20u << 20);         // z=1
  u16* VT = ws + (24u << 20);         // z=2 (transposed)
  u16* AO = ws + (28u << 20);
  // flash partials overlay the dead q/k/v region:
  u16* Op = ws;                            // bytes [0,16MB): 2 x 4M bf16
  float2* ml = (float2*)(ws + (8u << 20)); // bytes [16,17MB): 128K float2

  cvt_all<<<dim3(8192), dim3(256), 0, stream>>>(q, k, v, w_q, w_k, w_v, w_o, ws);
  gemm_proj<<<dim3(768), dim3(512), 0, stream>>>(qb, wqb, b_q, b_k, b_v, Qh);
  flash_attn5<<<dim3(16, 32, 2), dim3(512), 0, stream>>>(Qh, Kh, VT, Op, ml);
  combine<<<dim3(8192), dim3(256), 0, stream>>>((const uint32_t*)Op, ml, AO);
  gemm_out<<<dim3(256), dim3(512), 0, stream>>>(AO, wob, b_o, (float*)d_out);
}

// Round 13
// 156.150 us; speedup vs baseline: 1.1139x; 1.0441x over previous
//
#include <hip/hip_runtime.h>
#include <hip/hip_bf16.h>
#include <stdint.h>

// Problem constants: B=2, S=2048, D_MODEL=1024, H=16, Dk=64. M = B*S = 4096.
typedef unsigned short u16;
typedef __attribute__((ext_vector_type(8))) short short8;
typedef __attribute__((ext_vector_type(8))) __bf16 bf16x8;
typedef __attribute__((ext_vector_type(4))) float f32x4;
typedef __attribute__((ext_vector_type(4))) uint32_t u32x4;

#if defined(__has_builtin)
#if __has_builtin(__builtin_amdgcn_global_load_lds)
#define USE_GLLDS 1
#endif
#endif

// Fast 2^x: v_exp_f32 is the native HW op. (__exp2f collides with glibc.)
#if defined(__has_builtin)
#if __has_builtin(__builtin_amdgcn_exp2f)
#define HAVE_EXP2_BUILTIN 1
#endif
#endif
__device__ __forceinline__ float fexp2(float x) {
#ifdef HAVE_EXP2_BUILTIN
  return __builtin_amdgcn_exp2f(x);
#else
  return exp2f(x);
#endif
}

__device__ __forceinline__ u16 f2bf(float f) {
  __hip_bfloat16 h = __float2bfloat16(f);
  return __builtin_bit_cast(u16, h);
}

// Pack 2 fp32 -> 1 u32 of 2 bf16 (RNE) in ONE instruction (T12 recipe).
__device__ __forceinline__ uint32_t cvt_pk_bf16(float lo, float hi) {
  uint32_t w;
  asm("v_cvt_pk_bf16_f32 %0, %1, %2" : "=v"(w) : "v"(lo), "v"(hi));
  return w;
}

__device__ __forceinline__ f32x4 mfma16(bf16x8 a, bf16x8 b, f32x4 c) {
  return __builtin_amdgcn_mfma_f32_16x16x32_bf16(a, b, c, 0, 0, 0);
}

#ifdef USE_GLLDS
__device__ __forceinline__ void async_cp16(const void* g, void* l) {
  __builtin_amdgcn_global_load_lds(
      (const __attribute__((address_space(1))) void*)g,
      (__attribute__((address_space(3))) void*)l, 16, 0, 0);
}
#endif

// ---------------------------------------------------------------------------
// Kernel 1: fp32 -> bf16 conversion of q,k,v (4M each) and w_q,w_k,w_v,w_o (1M
// each) into one contiguous 16M-element bf16 region at the start of d_ws.
// ---------------------------------------------------------------------------
__global__ __launch_bounds__(256) void cvt_all(
    const float* __restrict__ q, const float* __restrict__ k,
    const float* __restrict__ v, const float* __restrict__ w0,
    const float* __restrict__ w1, const float* __restrict__ w2,
    const float* __restrict__ w3, u16* __restrict__ dst) {
  size_t i = ((size_t)blockIdx.x * 256 + threadIdx.x) * 8;
  const size_t M1 = 1u << 20;
  const float* s;
  size_t base;
  if (i < 4 * M1) { s = q; base = 0; }
  else if (i < 8 * M1) { s = k; base = 4 * M1; }
  else if (i < 12 * M1) { s = v; base = 8 * M1; }
  else if (i < 13 * M1) { s = w0; base = 12 * M1; }
  else if (i < 14 * M1) { s = w1; base = 13 * M1; }
  else if (i < 15 * M1) { s = w2; base = 14 * M1; }
  else { s = w3; base = 15 * M1; }
  const float4 a = *(const float4*)(s + (i - base));
  const float4 b = *(const float4*)(s + (i - base) + 4);
  short8 r;
  r[0] = (short)f2bf(a.x); r[1] = (short)f2bf(a.y);
  r[2] = (short)f2bf(a.z); r[3] = (short)f2bf(a.w);
  r[4] = (short)f2bf(b.x); r[5] = (short)f2bf(b.y);
  r[6] = (short)f2bf(b.z); r[7] = (short)f2bf(b.w);
  *(short8*)(dst + i) = r;
}

// ---------------------------------------------------------------------------
// GEMM core v2: 8 waves (512 threads), 128x128 tile, BK=64, SINGLE 32KB LDS
// buffer (m97 2-barrier structure). Wave tile = 64x32 (acc 4x2),
// 3 blocks/CU = 24 waves/CU of TLP hides the staging latency.
// Epilogue modes:
//   0: Q  -> bf16 split-head [B,H,S,64], scaled by 0.125*log2(e)  (exp2 dom.)
//   1: K  -> bf16 split-head [B,H,S,64]
//   2: V  -> bf16 TRANSPOSED split-head [B,H,64,S]  (V^T for the PV mfma)
//   3: fp32 row-major [4096,1024] (output projection)
// W passed PRE-OFFSET to the tile's first output row; n0 = local col base.
// ---------------------------------------------------------------------------
__device__ __forceinline__ void gemm_core8(const u16* __restrict__ X,
                                           const u16* __restrict__ W,
                                           const float* __restrict__ bias,
                                           void* __restrict__ outp, int mode,
                                           int m0, int n0) {
  __shared__ u16 Al[128 * 64];
  __shared__ u16 Bl[128 * 64];
  const int tid = threadIdx.x;
  const int wv = tid >> 6, l = tid & 63;
  const int wr = wv >> 2, wc = wv & 3;       // wave tile: rows wr*64, cols wc*32
  const int lrow = l & 15, lk = (l >> 4) * 8;

  f32x4 acc[4][2];
#pragma unroll
  for (int i = 0; i < 4; ++i)
#pragma unroll
    for (int j = 0; j < 2; ++j) acc[i][j] = (f32x4){0.f, 0.f, 0.f, 0.f};

  // staging: wave wv stages rows {wv*8..wv*8+7} and {+64} of each 128x64 tile
  const int srow = l >> 3;            // 0..7
  const int scol = (l & 7) * 8;       // 0..56
  const u16* Asrc = X + (size_t)(m0 + wv * 8 + srow) * 1024 + scol;
  const u16* Bsrc = W + (size_t)(wv * 8 + srow) * 1024 + scol;

  for (int kt = 0; kt < 1024; kt += 64) {
#ifdef USE_GLLDS
    async_cp16(Asrc + kt, &Al[(wv * 8) * 64]);
    async_cp16(Asrc + (size_t)64 * 1024 + kt, &Al[(wv * 8 + 64) * 64]);
    async_cp16(Bsrc + kt, &Bl[(wv * 8) * 64]);
    async_cp16(Bsrc + (size_t)64 * 1024 + kt, &Bl[(wv * 8 + 64) * 64]);
#else
    short8 a0 = *(const short8*)(Asrc + kt);
    short8 a1 = *(const short8*)(Asrc + (size_t)64 * 1024 + kt);
    short8 b0 = *(const short8*)(Bsrc + kt);
    short8 b1 = *(const short8*)(Bsrc + (size_t)64 * 1024 + kt);
    *(short8*)&Al[(wv * 8 + srow) * 64 + scol] = a0;
    *(short8*)&Al[(wv * 8 + 64 + srow) * 64 + scol] = a1;
    *(short8*)&Bl[(wv * 8 + srow) * 64 + scol] = b0;
    *(short8*)&Bl[(wv * 8 + 64 + srow) * 64 + scol] = b1;
#endif
    __syncthreads();   // drains staging (compiler inserts vmcnt/lgkm wait)
#pragma unroll
    for (int ks = 0; ks < 2; ++ks) {
      bf16x8 af[4], bf[2];
#pragma unroll
      for (int mf = 0; mf < 4; ++mf)
        af[mf] = *(const bf16x8*)&Al[(wr * 64 + mf * 16 + lrow) * 64 +
                                     ks * 32 + lk];
#pragma unroll
      for (int nf = 0; nf < 2; ++nf)
        bf[nf] = *(const bf16x8*)&Bl[(wc * 32 + nf * 16 + lrow) * 64 +
                                     ks * 32 + lk];
#pragma unroll
      for (int mf = 0; mf < 4; ++mf)
#pragma unroll
        for (int nf = 0; nf < 2; ++nf)
          acc[mf][nf] = mfma16(af[mf], bf[nf], acc[mf][nf]);
    }
    __syncthreads();   // protect buffer before next stage overwrites
  }

  const int rb = (l >> 4) * 4;
#pragma unroll
  for (int mf = 0; mf < 4; ++mf) {
#pragma unroll
    for (int nf = 0; nf < 2; ++nf) {
      const int gn = n0 + wc * 32 + nf * 16 + lrow;
      const float bi = bias[gn];
#pragma unroll
      for (int r = 0; r < 4; ++r) {
        const int gm = m0 + wr * 64 + mf * 16 + rb + r;
        float val = acc[mf][nf][r] + bi;
        const int b = gm >> 11, s = gm & 2047, h = gn >> 6, d = gn & 63;
        if (mode == 3) {
          ((float*)outp)[(size_t)gm * 1024 + gn] = val;
        } else if (mode == 2) {
          // V^T: [B,H,64,S]
          ((u16*)outp)[(((size_t)((b * 16 + h) * 64 + d)) << 11) + s] = f2bf(val);
        } else {
          if (mode == 0) val *= 0.18033688f;  // (1/8)*log2(e): exp2-domain
          ((u16*)outp)[(((size_t)((b * 16 + h) * 2048 + s)) << 6) + d] = f2bf(val);
        }
      }
    }
  }
}

// gemm_proj: fused grid over concatenated-N (N = 3072). 768 blocks; XCD-chunk
// swizzle (slot s -> xcd=s&7): chunk = 96 blocks (12 nx x 8 my).
__global__ __launch_bounds__(512, 6) void gemm_proj(
    const u16* __restrict__ qb, const u16* __restrict__ wqb,
    const float* __restrict__ b_q, const float* __restrict__ b_k,
    const float* __restrict__ b_v, u16* __restrict__ Qh) {
  const int s = blockIdx.x;
  const int xcd = s & 7, c = s >> 3;              // c in [0,96)
  const int nx = (xcd >> 2) * 12 + (c % 12);      // [0,24)
  const int my = (xcd & 3) * 8 + (c / 12);        // [0,32)
  const int z = nx >> 3, nxl = nx & 7;
  const float* bias = (z == 0) ? b_q : ((z == 1) ? b_k : b_v);
  gemm_core8(qb + ((size_t)z << 22), wqb + ((size_t)nx << 17), bias,
             Qh + ((size_t)z << 22), z, my * 128, nxl * 128);
}

// gemm_out: 256 blocks; chunk = 32 blocks (4 nx x 8 my).
__global__ __launch_bounds__(512, 6) void gemm_out(
    const u16* __restrict__ X, const u16* __restrict__ W,
    const float* __restrict__ bias, float* __restrict__ out) {
  const int s = blockIdx.x;
  const int xcd = s & 7, c = s >> 3;              // c in [0,32)
  const int nx = (xcd >> 2) * 4 + (c & 3);        // [0,8)
  const int my = (xcd & 3) * 8 + (c >> 2);        // [0,32)
  gemm_core8(X, W + ((size_t)nx << 17), bias, out, 3, my * 128, nx * 128);
}

// ---------------------------------------------------------------------------
// Flash attention v7: v5's PROVEN sync structure (2 barriers per staging slot,
// T14 issue-early / write-late, single buffer per tile-half) with KVBLK=128:
// two 64-col halves per barrier pair. Halves use separate 64x64 buffers so
// every address formula is byte-identical to v5. Halves share the per-wave
// P slab (in-order DS within a wave; true-dependence keeps order).
// Fixed costs halved vs v5: 16 barrier pairs (was 32), one max-tree/shfl/
// defer-check/ps-reduce per 128 cols (was per 64).
// ---------------------------------------------------------------------------
__global__ __launch_bounds__(512, 4) void flash_attn7(
    const u16* __restrict__ Qh, const u16* __restrict__ Kh,
    const u16* __restrict__ VT, u16* __restrict__ Op,
    float2* __restrict__ ml) {
  __shared__ __align__(16) u16 Kbuf[2][4096];    // halves 0,1 of 128-col group
  __shared__ __align__(16) u16 Vbuf[2][4096];
  __shared__ __align__(16) uint32_t Pl[8 * 576]; // per-wave 16 rows x 36 dw

  const int tid = threadIdx.x;
  const int wv = tid >> 6, l = tid & 63;
  const int q = l & 15, g = l >> 4;

  // XCD swizzle: dispatch slot s -> original block o = (s%8)*128 + s/8.
  const int s_lin = blockIdx.x + (blockIdx.y << 4) + (blockIdx.z << 9);
  const int o = ((s_lin & 7) << 7) + (s_lin >> 3);
  const int qt = o & 15, bh = (o >> 4) & 31, z = o >> 9;

  const u16* Qp = Qh + ((size_t)bh * 2048 + qt * 128 + wv * 16) * 64;
  const u16* Kp = Kh + (size_t)bh * 2048 * 64;
  const u16* Vp = VT + (size_t)bh * 64 * 2048;

  // Q fragments (B-operand): lane holds Q[q=l&15][d = ks*32 + g*8 .. +7]
  bf16x8 qf[2];
  qf[0] = *(const bf16x8*)(Qp + q * 64 + g * 8);
  qf[1] = *(const bf16x8*)(Qp + q * 64 + 32 + g * 8);

  f32x4 o_acc[4];
#pragma unroll
  for (int df = 0; df < 4; ++df) o_acc[df] = (f32x4){0.f, 0.f, 0.f, 0.f};
  float m = -1e30f, ls = 0.f;

  const int srow = l >> 3;                       // 0..7 within wave's 8 rows
  const int scolq = (l & 7) ^ srow;              // inverse-swizzled 16B chunk
  const int pbase = wv * 576 + q * 36;
  const char* kb0 = (const char*)&Kbuf[0][0];
  const char* kb1 = (const char*)&Kbuf[1][0];
  const char* vb0 = (const char*)&Vbuf[0][0];
  const char* vb1 = (const char*)&Vbuf[1][0];
  const int rsw = (q & 7) << 4;                  // read swizzle (byte)

  // per-thread global staging pointers; a 128-col group = 128 K-rows / cols
  const u16* kg = Kp + (size_t)(z * 1024 + wv * 8 + srow) * 64 + scolq * 8;
  const u16* vg = Vp + (size_t)(wv * 8 + srow) * 2048 + z * 1024 + scolq * 8;

  // prologue: stage group 0 (both halves) through regs
  {
    short8 k0 = *(const short8*)kg;
    short8 k1 = *(const short8*)(kg + 4096);
    short8 v0 = *(const short8*)vg;
    short8 v1 = *(const short8*)(vg + 64);
    *(short8*)&Kbuf[0][wv * 512 + l * 8] = k0;
    *(short8*)&Kbuf[1][wv * 512 + l * 8] = k1;
    *(short8*)&Vbuf[0][wv * 512 + l * 8] = v0;
    *(short8*)&Vbuf[1][wv * 512 + l * 8] = v1;
  }
  kg += 8192;
  vg += 128;
  __syncthreads();

  for (int tt = 0; tt < 8; ++tt) {
    // ---- T14 issue-early: next group's loads go in flight NOW
    short8 kr0, kr1, vr0, vr1;
    if (tt < 7) {
      kr0 = *(const short8*)kg;
      kr1 = *(const short8*)(kg + 4096);
      vr0 = *(const short8*)vg;
      vr1 = *(const short8*)(vg + 64);
      kg += 8192;
      vg += 128;
    }

    // ---- S = K . Q' for both halves: sh[h][nj] holds k = h*64+nj*16+4g+r
    f32x4 s0[4], s1[4];
#pragma unroll
    for (int nj = 0; nj < 4; ++nj) {
      s0[nj] = (f32x4){0.f, 0.f, 0.f, 0.f};
      s1[nj] = (f32x4){0.f, 0.f, 0.f, 0.f};
    }
#pragma unroll
    for (int ks = 0; ks < 2; ++ks) {
#pragma unroll
      for (int nj = 0; nj < 4; ++nj) {
        const int off = (nj * 16 + q) * 128 + (((ks * 4 + g) << 4) ^ rsw);
        bf16x8 kf0 = *(const bf16x8*)(kb0 + off);
        bf16x8 kf1 = *(const bf16x8*)(kb1 + off);
        s0[nj] = mfma16(kf0, qf[ks], s0[nj]);
        s1[nj] = mfma16(kf1, qf[ks], s1[nj]);
      }
    }

    // ---- one online-softmax pass over all 32 values (row q, 4 lanes)
    float mt = s0[0][0];
#pragma unroll
    for (int nj = 0; nj < 4; ++nj)
#pragma unroll
      for (int r = 0; r < 4; ++r) {
        mt = fmaxf(mt, s0[nj][r]);
        mt = fmaxf(mt, s1[nj][r]);
      }
    mt = fmaxf(mt, __shfl_xor(mt, 16));
    mt = fmaxf(mt, __shfl_xor(mt, 32));
    if (!__all(mt <= m + 8.f)) {               // defer-max: rescale rarely
      const float nm = fmaxf(m, mt);
      const float rf = fexp2(m - nm);
      m = nm;
      ls *= rf;
#pragma unroll
      for (int df = 0; df < 4; ++df) o_acc[df] *= rf;
    }
    float ps = 0.f;
#pragma unroll
    for (int nj = 0; nj < 4; ++nj)
#pragma unroll
      for (int r = 0; r < 4; ++r) {
        s0[nj][r] = fexp2(s0[nj][r] - m);
        s1[nj][r] = fexp2(s1[nj][r] - m);
        ps += s0[nj][r] + s1[nj][r];
      }
    ps += __shfl_xor(ps, 16);
    ps += __shfl_xor(ps, 32);
    ls += ps;

    // ---- half 0: P -> LDS, then PV (same-wave slab, in-order DS)
#pragma unroll
    for (int nj = 0; nj < 4; ++nj)
#pragma unroll
      for (int pp = 0; pp < 2; ++pp)
        Pl[pbase + nj * 8 + g * 2 + pp] =
            cvt_pk_bf16(s0[nj][2 * pp], s0[nj][2 * pp + 1]);
#pragma unroll
    for (int ks = 0; ks < 2; ++ks) {
      u32x4 pw = *(const u32x4*)&Pl[pbase + ks * 16 + 4 * g];
      bf16x8 pf = __builtin_bit_cast(bf16x8, pw);
#pragma unroll
      for (int df = 0; df < 4; ++df) {
        bf16x8 vf = *(const bf16x8*)(vb0 + (df * 16 + q) * 128 +
                                     (((ks * 4 + g) << 4) ^ rsw));
        o_acc[df] = mfma16(vf, pf, o_acc[df]);
      }
    }

    // ---- half 1: P -> LDS (same addresses; true dep keeps order), then PV
#pragma unroll
    for (int nj = 0; nj < 4; ++nj)
#pragma unroll
      for (int pp = 0; pp < 2; ++pp)
        Pl[pbase + nj * 8 + g * 2 + pp] =
            cvt_pk_bf16(s1[nj][2 * pp], s1[nj][2 * pp + 1]);
#pragma unroll
    for (int ks = 0; ks < 2; ++ks) {
      u32x4 pw = *(const u32x4*)&Pl[pbase + ks * 16 + 4 * g];
      bf16x8 pf = __builtin_bit_cast(bf16x8, pw);
#pragma unroll
      for (int df = 0; df < 4; ++df) {
        bf16x8 vf = *(const bf16x8*)(vb1 + (df * 16 + q) * 128 +
                                     (((ks * 4 + g) << 4) ^ rsw));
        o_acc[df] = mfma16(vf, pf, o_acc[df]);
      }
    }

    // ---- v5 write-late slot: all waves done reading K/V LDS, then overwrite
    __syncthreads();
    if (tt < 7) {
      *(short8*)&Kbuf[0][wv * 512 + l * 8] = kr0;
      *(short8*)&Kbuf[1][wv * 512 + l * 8] = kr1;
      *(short8*)&Vbuf[0][wv * 512 + l * 8] = vr0;
      *(short8*)&Vbuf[1][wv * 512 + l * 8] = vr1;
    }
    __syncthreads();
  }

  // ---- epilogue: write NORMALIZED partial O (bf16) + (m, ls) per row
  const float inv = 1.f / ls;
  const int rowb = qt * 128 + wv * 16 + q;
  const size_t prow = (size_t)(z * 32 + bh) * 2048 + rowb;
  u16* Po = Op + (prow << 6);
#pragma unroll
  for (int df = 0; df < 4; ++df)
#pragma unroll
    for (int pp = 0; pp < 2; ++pp) {
      uint32_t w = cvt_pk_bf16(o_acc[df][2 * pp] * inv,
                               o_acc[df][2 * pp + 1] * inv);
      *(uint32_t*)(Po + df * 16 + 4 * g + 2 * pp) = w;
    }
  if (g == 0) ml[prow] = make_float2(m, ls);
}

// ---------------------------------------------------------------------------
// Combine the two KV-half partials: O = (w1*O1n + w2*O2n), w_i ~ ls_i*2^m_i.
// ---------------------------------------------------------------------------
__global__ __launch_bounds__(256) void combine(
    const uint32_t* __restrict__ Op32, const float2* __restrict__ ml,
    u16* __restrict__ AO) {
  const int j = blockIdx.x * 256 + threadIdx.x;   // [0, 2M)
  const int rowid = j >> 5, w5 = j & 31;
  const float2 a = ml[rowid];
  const float2 c = ml[(1 << 16) + rowid];
  const float M = fmaxf(a.x, c.x);
  float w1 = a.y * fexp2(a.x - M);
  float w2 = c.y * fexp2(c.x - M);
  const float inv = 1.f / (w1 + w2);
  w1 *= inv;
  w2 *= inv;
  const uint32_t p1 = Op32[j];
  const uint32_t p2 = Op32[(1u << 21) + j];
  const float lo = w1 * __builtin_bit_cast(float, p1 << 16) +
                   w2 * __builtin_bit_cast(float, p2 << 16);
  const float hi = w1 * __builtin_bit_cast(float, p1 & 0xffff0000u) +
                   w2 * __builtin_bit_cast(float, p2 & 0xffff0000u);
  const uint32_t outw = cvt_pk_bf16(lo, hi);
  const int bh = rowid >> 11, s = rowid & 2047, b = bh >> 4, h = bh & 15;
  ((uint32_t*)AO)[((size_t)(b * 2048 + s) << 9) + h * 32 + w5] = outw;
}

// ---------------------------------------------------------------------------
extern "C" void kernel_launch(void* const* d_in, const int* in_sizes, int n_in,
                              void* d_out, int out_size, void* d_ws,
                              size_t ws_size, hipStream_t stream) {
  const float* q = (const float*)d_in[0];
  const float* k = (const float*)d_in[1];
  const float* v = (const float*)d_in[2];
  const float* w_q = (const float*)d_in[3];
  const float* b_q = (const float*)d_in[4];
  const float* w_k = (const float*)d_in[5];
  const float* b_k = (const float*)d_in[6];
  const float* w_v = (const float*)d_in[7];
  const float* b_v = (const float*)d_in[8];
  const float* w_o = (const float*)d_in[9];
  const float* b_o = (const float*)d_in[10];

  // ws layout (u16 elems): [0,12M) q/k/v bf16 (DEAD after gemm_proj; reused
  // as flash partials), [12M,16M) weights bf16, [16M,20M) Qh, [20M,24M) Kh,
  // [24M,28M) V^T, [28M,32M) attn out. 64 MB total.
  u16* ws = (u16*)d_ws;
  u16* qb = ws;                       // + z*4M for k,v
  u16* wqb = ws + (12u << 20);        // + z*1M for wk,wv (contiguous concat)
  u16* wob = ws + (15u << 20);
  u16* Qh = ws + (16u << 20);         // z=0 (pre-scaled by 0.125*log2e)
  u16* Kh = ws + (20u << 20);         // z=1
  u16* VT = ws + (24u << 20);         // z=2 (transposed)
  u16* AO = ws + (28u << 20);
  // flash partials overlay the dead q/k/v region:
  u16* Op = ws;                            // bytes [0,16MB): 2 x 4M bf16
  float2* ml = (float2*)(ws + (8u << 20)); // bytes [16,17MB): 128K float2

  cvt_all<<<dim3(8192), dim3(256), 0, stream>>>(q, k, v, w_q, w_k, w_v, w_o, ws);
  gemm_proj<<<dim3(768), dim3(512), 0, stream>>>(qb, wqb, b_q, b_k, b_v, Qh);
  flash_attn7<<<dim3(16, 32, 2), dim3(512), 0, stream>>>(Qh, Kh, VT, Op, ml);
  combine<<<dim3(8192), dim3(256), 0, stream>>>((const uint32_t*)Op, ml, AO);
  gemm_out<<<dim3(256), dim3(512), 0, stream>>>(AO, wob, b_o, (float*)d_out);
}

// Round 14
// 144.647 us; speedup vs baseline: 1.2025x; 1.0795x over previous
//
#include <hip/hip_runtime.h>
#include <hip/hip_bf16.h>
#include <stdint.h>

// Problem constants: B=2, S=2048, D_MODEL=1024, H=16, Dk=64. M = B*S = 4096.
typedef unsigned short u16;
typedef __attribute__((ext_vector_type(8))) short short8;
typedef __attribute__((ext_vector_type(8))) __bf16 bf16x8;
typedef __attribute__((ext_vector_type(4))) float f32x4;
typedef __attribute__((ext_vector_type(4))) uint32_t u32x4;

#if defined(__has_builtin)
#if __has_builtin(__builtin_amdgcn_global_load_lds)
#define USE_GLLDS 1
#endif
#endif

// Fast 2^x: v_exp_f32 is the native HW op. (__exp2f collides with glibc.)
#if defined(__has_builtin)
#if __has_builtin(__builtin_amdgcn_exp2f)
#define HAVE_EXP2_BUILTIN 1
#endif
#endif
__device__ __forceinline__ float fexp2(float x) {
#ifdef HAVE_EXP2_BUILTIN
  return __builtin_amdgcn_exp2f(x);
#else
  return exp2f(x);
#endif
}

__device__ __forceinline__ u16 f2bf(float f) {
  __hip_bfloat16 h = __float2bfloat16(f);
  return __builtin_bit_cast(u16, h);
}

// Pack 2 fp32 -> 1 u32 of 2 bf16 (RNE) in ONE instruction (T12 recipe).
__device__ __forceinline__ uint32_t cvt_pk_bf16(float lo, float hi) {
  uint32_t w;
  asm("v_cvt_pk_bf16_f32 %0, %1, %2" : "=v"(w) : "v"(lo), "v"(hi));
  return w;
}

__device__ __forceinline__ f32x4 mfma16(bf16x8 a, bf16x8 b, f32x4 c) {
  return __builtin_amdgcn_mfma_f32_16x16x32_bf16(a, b, c, 0, 0, 0);
}

#ifdef USE_GLLDS
__device__ __forceinline__ void async_cp16(const void* g, void* l) {
  __builtin_amdgcn_global_load_lds(
      (const __attribute__((address_space(1))) void*)g,
      (__attribute__((address_space(3))) void*)l, 16, 0, 0);
}
#endif

// ---------------------------------------------------------------------------
// Kernel 1: fp32 -> bf16 conversion of q,k,v (4M each) and w_q,w_k,w_v,w_o (1M
// each) into one contiguous 16M-element bf16 region at the start of d_ws.
// ---------------------------------------------------------------------------
__global__ __launch_bounds__(256) void cvt_all(
    const float* __restrict__ q, const float* __restrict__ k,
    const float* __restrict__ v, const float* __restrict__ w0,
    const float* __restrict__ w1, const float* __restrict__ w2,
    const float* __restrict__ w3, u16* __restrict__ dst) {
  size_t i = ((size_t)blockIdx.x * 256 + threadIdx.x) * 8;
  const size_t M1 = 1u << 20;
  const float* s;
  size_t base;
  if (i < 4 * M1) { s = q; base = 0; }
  else if (i < 8 * M1) { s = k; base = 4 * M1; }
  else if (i < 12 * M1) { s = v; base = 8 * M1; }
  else if (i < 13 * M1) { s = w0; base = 12 * M1; }
  else if (i < 14 * M1) { s = w1; base = 13 * M1; }
  else if (i < 15 * M1) { s = w2; base = 14 * M1; }
  else { s = w3; base = 15 * M1; }
  const float4 a = *(const float4*)(s + (i - base));
  const float4 b = *(const float4*)(s + (i - base) + 4);
  short8 r;
  r[0] = (short)f2bf(a.x); r[1] = (short)f2bf(a.y);
  r[2] = (short)f2bf(a.z); r[3] = (short)f2bf(a.w);
  r[4] = (short)f2bf(b.x); r[5] = (short)f2bf(b.y);
  r[6] = (short)f2bf(b.z); r[7] = (short)f2bf(b.w);
  *(short8*)(dst + i) = r;
}

// ---------------------------------------------------------------------------
// GEMM core v3: 8 waves, 128x128 tile, BK=64, single 32KB LDS buffer, PLUS
// T2 XOR-swizzle on the LDS tiles (rule #21 both-sides):
//   - global SOURCE chunk is inverse-swizzled: gchunk = (l&7) ^ srow
//     (LDS dest stays linear -- global_load_lds compatible), so
//     LDS[row][c] = G[row][c ^ (row&7)] (16B chunks).
//   - every ds_read_b128 XORs (row&7) into its quad index.
// Pre-swizzle bank math: lanes 0-15 read 16 rows at one column -> 128B row
// stride = same bank = 16-way conflict (was 38% of kernel cycles). Post:
// 2 lanes/bank = free (m136).
// Epilogue modes:
//   0: Q  -> bf16 split-head [B,H,S,64], scaled by 0.125*log2(e)  (exp2 dom.)
//   1: K  -> bf16 split-head [B,H,S,64]
//   2: V  -> bf16 TRANSPOSED split-head [B,H,64,S]  (V^T for the PV mfma)
//   3: fp32 row-major [4096,1024] (output projection)
// W passed PRE-OFFSET to the tile's first output row; n0 = local col base.
// ---------------------------------------------------------------------------
__device__ __forceinline__ void gemm_core8(const u16* __restrict__ X,
                                           const u16* __restrict__ W,
                                           const float* __restrict__ bias,
                                           void* __restrict__ outp, int mode,
                                           int m0, int n0) {
  __shared__ u16 Al[128 * 64];
  __shared__ u16 Bl[128 * 64];
  const int tid = threadIdx.x;
  const int wv = tid >> 6, l = tid & 63;
  const int wr = wv >> 2, wc = wv & 3;       // wave tile: rows wr*64, cols wc*32
  const int lrow = l & 15, g = l >> 4;
  const int rswe = (lrow & 7) << 3;          // read swizzle (u16 elements)

  f32x4 acc[4][2];
#pragma unroll
  for (int i = 0; i < 4; ++i)
#pragma unroll
    for (int j = 0; j < 2; ++j) acc[i][j] = (f32x4){0.f, 0.f, 0.f, 0.f};

  // staging: wave wv stages rows {wv*8..wv*8+7} and {+64} of each 128x64 tile.
  // Global chunk is INVERSE-swizzled; LDS dest is linear (lane-order).
  const int srow = l >> 3;                   // 0..7
  const int gcol = ((l & 7) ^ srow) * 8;     // inverse-swizzled 16B chunk
  const u16* Asrc = X + (size_t)(m0 + wv * 8 + srow) * 1024 + gcol;
  const u16* Bsrc = W + (size_t)(wv * 8 + srow) * 1024 + gcol;

  for (int kt = 0; kt < 1024; kt += 64) {
#ifdef USE_GLLDS
    async_cp16(Asrc + kt, &Al[(wv * 8) * 64]);
    async_cp16(Asrc + (size_t)64 * 1024 + kt, &Al[(wv * 8 + 64) * 64]);
    async_cp16(Bsrc + kt, &Bl[(wv * 8) * 64]);
    async_cp16(Bsrc + (size_t)64 * 1024 + kt, &Bl[(wv * 8 + 64) * 64]);
#else
    short8 a0 = *(const short8*)(Asrc + kt);
    short8 a1 = *(const short8*)(Asrc + (size_t)64 * 1024 + kt);
    short8 b0 = *(const short8*)(Bsrc + kt);
    short8 b1 = *(const short8*)(Bsrc + (size_t)64 * 1024 + kt);
    *(short8*)&Al[(wv * 8 + srow) * 64 + (l & 7) * 8] = a0;
    *(short8*)&Al[(wv * 8 + 64 + srow) * 64 + (l & 7) * 8] = a1;
    *(short8*)&Bl[(wv * 8 + srow) * 64 + (l & 7) * 8] = b0;
    *(short8*)&Bl[(wv * 8 + 64 + srow) * 64 + (l & 7) * 8] = b1;
#endif
    __syncthreads();   // drains staging (compiler inserts vmcnt/lgkm wait)
#pragma unroll
    for (int ks = 0; ks < 2; ++ks) {
      bf16x8 af[4], bf[2];
      const int qoff = (((ks * 4 + g) << 3) ^ rswe);  // swizzled quad offset
#pragma unroll
      for (int mf = 0; mf < 4; ++mf)
        af[mf] = *(const bf16x8*)&Al[(wr * 64 + mf * 16 + lrow) * 64 + qoff];
#pragma unroll
      for (int nf = 0; nf < 2; ++nf)
        bf[nf] = *(const bf16x8*)&Bl[(wc * 32 + nf * 16 + lrow) * 64 + qoff];
#pragma unroll
      for (int mf = 0; mf < 4; ++mf)
#pragma unroll
        for (int nf = 0; nf < 2; ++nf)
          acc[mf][nf] = mfma16(af[mf], bf[nf], acc[mf][nf]);
    }
    __syncthreads();   // protect buffer before next stage overwrites
  }

  const int rb = (l >> 4) * 4;
#pragma unroll
  for (int mf = 0; mf < 4; ++mf) {
#pragma unroll
    for (int nf = 0; nf < 2; ++nf) {
      const int gn = n0 + wc * 32 + nf * 16 + lrow;
      const float bi = bias[gn];
#pragma unroll
      for (int r = 0; r < 4; ++r) {
        const int gm = m0 + wr * 64 + mf * 16 + rb + r;
        float val = acc[mf][nf][r] + bi;
        const int b = gm >> 11, s = gm & 2047, h = gn >> 6, d = gn & 63;
        if (mode == 3) {
          ((float*)outp)[(size_t)gm * 1024 + gn] = val;
        } else if (mode == 2) {
          // V^T: [B,H,64,S]
          ((u16*)outp)[(((size_t)((b * 16 + h) * 64 + d)) << 11) + s] = f2bf(val);
        } else {
          if (mode == 0) val *= 0.18033688f;  // (1/8)*log2(e): exp2-domain
          ((u16*)outp)[(((size_t)((b * 16 + h) * 2048 + s)) << 6) + d] = f2bf(val);
        }
      }
    }
  }
}

// gemm_proj: fused grid over concatenated-N (N = 3072). 768 blocks; XCD-chunk
// swizzle (slot s -> xcd=s&7): chunk = 96 blocks (12 nx x 8 my).
__global__ __launch_bounds__(512, 6) void gemm_proj(
    const u16* __restrict__ qb, const u16* __restrict__ wqb,
    const float* __restrict__ b_q, const float* __restrict__ b_k,
    const float* __restrict__ b_v, u16* __restrict__ Qh) {
  const int s = blockIdx.x;
  const int xcd = s & 7, c = s >> 3;              // c in [0,96)
  const int nx = (xcd >> 2) * 12 + (c % 12);      // [0,24)
  const int my = (xcd & 3) * 8 + (c / 12);        // [0,32)
  const int z = nx >> 3, nxl = nx & 7;
  const float* bias = (z == 0) ? b_q : ((z == 1) ? b_k : b_v);
  gemm_core8(qb + ((size_t)z << 22), wqb + ((size_t)nx << 17), bias,
             Qh + ((size_t)z << 22), z, my * 128, nxl * 128);
}

// gemm_out: 256 blocks; chunk = 32 blocks (4 nx x 8 my).
__global__ __launch_bounds__(512, 6) void gemm_out(
    const u16* __restrict__ X, const u16* __restrict__ W,
    const float* __restrict__ bias, float* __restrict__ out) {
  const int s = blockIdx.x;
  const int xcd = s & 7, c = s >> 3;              // c in [0,32)
  const int nx = (xcd >> 2) * 4 + (c & 3);        // [0,8)
  const int my = (xcd & 3) * 8 + (c >> 2);        // [0,32)
  gemm_core8(X, W + ((size_t)nx << 17), bias, out, 3, my * 128, nx * 128);
}

// ---------------------------------------------------------------------------
// Flash attention v7: v5's PROVEN sync structure (2 barriers per staging slot,
// T14 issue-early / write-late, single buffer per tile-half) with KVBLK=128:
// two 64-col halves per barrier pair. (Unchanged from round 13.)
// ---------------------------------------------------------------------------
__global__ __launch_bounds__(512, 4) void flash_attn7(
    const u16* __restrict__ Qh, const u16* __restrict__ Kh,
    const u16* __restrict__ VT, u16* __restrict__ Op,
    float2* __restrict__ ml) {
  __shared__ __align__(16) u16 Kbuf[2][4096];    // halves 0,1 of 128-col group
  __shared__ __align__(16) u16 Vbuf[2][4096];
  __shared__ __align__(16) uint32_t Pl[8 * 576]; // per-wave 16 rows x 36 dw

  const int tid = threadIdx.x;
  const int wv = tid >> 6, l = tid & 63;
  const int q = l & 15, g = l >> 4;

  // XCD swizzle: dispatch slot s -> original block o = (s%8)*128 + s/8.
  const int s_lin = blockIdx.x + (blockIdx.y << 4) + (blockIdx.z << 9);
  const int o = ((s_lin & 7) << 7) + (s_lin >> 3);
  const int qt = o & 15, bh = (o >> 4) & 31, z = o >> 9;

  const u16* Qp = Qh + ((size_t)bh * 2048 + qt * 128 + wv * 16) * 64;
  const u16* Kp = Kh + (size_t)bh * 2048 * 64;
  const u16* Vp = VT + (size_t)bh * 64 * 2048;

  // Q fragments (B-operand): lane holds Q[q=l&15][d = ks*32 + g*8 .. +7]
  bf16x8 qf[2];
  qf[0] = *(const bf16x8*)(Qp + q * 64 + g * 8);
  qf[1] = *(const bf16x8*)(Qp + q * 64 + 32 + g * 8);

  f32x4 o_acc[4];
#pragma unroll
  for (int df = 0; df < 4; ++df) o_acc[df] = (f32x4){0.f, 0.f, 0.f, 0.f};
  float m = -1e30f, ls = 0.f;

  const int srow = l >> 3;                       // 0..7 within wave's 8 rows
  const int scolq = (l & 7) ^ srow;              // inverse-swizzled 16B chunk
  const int pbase = wv * 576 + q * 36;
  const char* kb0 = (const char*)&Kbuf[0][0];
  const char* kb1 = (const char*)&Kbuf[1][0];
  const char* vb0 = (const char*)&Vbuf[0][0];
  const char* vb1 = (const char*)&Vbuf[1][0];
  const int rsw = (q & 7) << 4;                  // read swizzle (byte)

  // per-thread global staging pointers; a 128-col group = 128 K-rows / cols
  const u16* kg = Kp + (size_t)(z * 1024 + wv * 8 + srow) * 64 + scolq * 8;
  const u16* vg = Vp + (size_t)(wv * 8 + srow) * 2048 + z * 1024 + scolq * 8;

  // prologue: stage group 0 (both halves) through regs
  {
    short8 k0 = *(const short8*)kg;
    short8 k1 = *(const short8*)(kg + 4096);
    short8 v0 = *(const short8*)vg;
    short8 v1 = *(const short8*)(vg + 64);
    *(short8*)&Kbuf[0][wv * 512 + l * 8] = k0;
    *(short8*)&Kbuf[1][wv * 512 + l * 8] = k1;
    *(short8*)&Vbuf[0][wv * 512 + l * 8] = v0;
    *(short8*)&Vbuf[1][wv * 512 + l * 8] = v1;
  }
  kg += 8192;
  vg += 128;
  __syncthreads();

  for (int tt = 0; tt < 8; ++tt) {
    // ---- T14 issue-early: next group's loads go in flight NOW
    short8 kr0, kr1, vr0, vr1;
    if (tt < 7) {
      kr0 = *(const short8*)kg;
      kr1 = *(const short8*)(kg + 4096);
      vr0 = *(const short8*)vg;
      vr1 = *(const short8*)(vg + 64);
      kg += 8192;
      vg += 128;
    }

    // ---- S = K . Q' for both halves: sh[h][nj] holds k = h*64+nj*16+4g+r
    f32x4 s0[4], s1[4];
#pragma unroll
    for (int nj = 0; nj < 4; ++nj) {
      s0[nj] = (f32x4){0.f, 0.f, 0.f, 0.f};
      s1[nj] = (f32x4){0.f, 0.f, 0.f, 0.f};
    }
#pragma unroll
    for (int ks = 0; ks < 2; ++ks) {
#pragma unroll
      for (int nj = 0; nj < 4; ++nj) {
        const int off = (nj * 16 + q) * 128 + (((ks * 4 + g) << 4) ^ rsw);
        bf16x8 kf0 = *(const bf16x8*)(kb0 + off);
        bf16x8 kf1 = *(const bf16x8*)(kb1 + off);
        s0[nj] = mfma16(kf0, qf[ks], s0[nj]);
        s1[nj] = mfma16(kf1, qf[ks], s1[nj]);
      }
    }

    // ---- one online-softmax pass over all 32 values (row q, 4 lanes)
    float mt = s0[0][0];
#pragma unroll
    for (int nj = 0; nj < 4; ++nj)
#pragma unroll
      for (int r = 0; r < 4; ++r) {
        mt = fmaxf(mt, s0[nj][r]);
        mt = fmaxf(mt, s1[nj][r]);
      }
    mt = fmaxf(mt, __shfl_xor(mt, 16));
    mt = fmaxf(mt, __shfl_xor(mt, 32));
    if (!__all(mt <= m + 8.f)) {               // defer-max: rescale rarely
      const float nm = fmaxf(m, mt);
      const float rf = fexp2(m - nm);
      m = nm;
      ls *= rf;
#pragma unroll
      for (int df = 0; df < 4; ++df) o_acc[df] *= rf;
    }
    float ps = 0.f;
#pragma unroll
    for (int nj = 0; nj < 4; ++nj)
#pragma unroll
      for (int r = 0; r < 4; ++r) {
        s0[nj][r] = fexp2(s0[nj][r] - m);
        s1[nj][r] = fexp2(s1[nj][r] - m);
        ps += s0[nj][r] + s1[nj][r];
      }
    ps += __shfl_xor(ps, 16);
    ps += __shfl_xor(ps, 32);
    ls += ps;

    // ---- half 0: P -> LDS, then PV (same-wave slab, in-order DS)
#pragma unroll
    for (int nj = 0; nj < 4; ++nj)
#pragma unroll
      for (int pp = 0; pp < 2; ++pp)
        Pl[pbase + nj * 8 + g * 2 + pp] =
            cvt_pk_bf16(s0[nj][2 * pp], s0[nj][2 * pp + 1]);
#pragma unroll
    for (int ks = 0; ks < 2; ++ks) {
      u32x4 pw = *(const u32x4*)&Pl[pbase + ks * 16 + 4 * g];
      bf16x8 pf = __builtin_bit_cast(bf16x8, pw);
#pragma unroll
      for (int df = 0; df < 4; ++df) {
        bf16x8 vf = *(const bf16x8*)(vb0 + (df * 16 + q) * 128 +
                                     (((ks * 4 + g) << 4) ^ rsw));
        o_acc[df] = mfma16(vf, pf, o_acc[df]);
      }
    }

    // ---- half 1: P -> LDS (same addresses; true dep keeps order), then PV
#pragma unroll
    for (int nj = 0; nj < 4; ++nj)
#pragma unroll
      for (int pp = 0; pp < 2; ++pp)
        Pl[pbase + nj * 8 + g * 2 + pp] =
            cvt_pk_bf16(s1[nj][2 * pp], s1[nj][2 * pp + 1]);
#pragma unroll
    for (int ks = 0; ks < 2; ++ks) {
      u32x4 pw = *(const u32x4*)&Pl[pbase + ks * 16 + 4 * g];
      bf16x8 pf = __builtin_bit_cast(bf16x8, pw);
#pragma unroll
      for (int df = 0; df < 4; ++df) {
        bf16x8 vf = *(const bf16x8*)(vb1 + (df * 16 + q) * 128 +
                                     (((ks * 4 + g) << 4) ^ rsw));
        o_acc[df] = mfma16(vf, pf, o_acc[df]);
      }
    }

    // ---- v5 write-late slot: all waves done reading K/V LDS, then overwrite
    __syncthreads();
    if (tt < 7) {
      *(short8*)&Kbuf[0][wv * 512 + l * 8] = kr0;
      *(short8*)&Kbuf[1][wv * 512 + l * 8] = kr1;
      *(short8*)&Vbuf[0][wv * 512 + l * 8] = vr0;
      *(short8*)&Vbuf[1][wv * 512 + l * 8] = vr1;
    }
    __syncthreads();
  }

  // ---- epilogue: write NORMALIZED partial O (bf16) + (m, ls) per row
  const float inv = 1.f / ls;
  const int rowb = qt * 128 + wv * 16 + q;
  const size_t prow = (size_t)(z * 32 + bh) * 2048 + rowb;
  u16* Po = Op + (prow << 6);
#pragma unroll
  for (int df = 0; df < 4; ++df)
#pragma unroll
    for (int pp = 0; pp < 2; ++pp) {
      uint32_t w = cvt_pk_bf16(o_acc[df][2 * pp] * inv,
                               o_acc[df][2 * pp + 1] * inv);
      *(uint32_t*)(Po + df * 16 + 4 * g + 2 * pp) = w;
    }
  if (g == 0) ml[prow] = make_float2(m, ls);
}

// ---------------------------------------------------------------------------
// Combine the two KV-half partials: O = (w1*O1n + w2*O2n), w_i ~ ls_i*2^m_i.
// ---------------------------------------------------------------------------
__global__ __launch_bounds__(256) void combine(
    const uint32_t* __restrict__ Op32, const float2* __restrict__ ml,
    u16* __restrict__ AO) {
  const int j = blockIdx.x * 256 + threadIdx.x;   // [0, 2M)
  const int rowid = j >> 5, w5 = j & 31;
  const float2 a = ml[rowid];
  const float2 c = ml[(1 << 16) + rowid];
  const float M = fmaxf(a.x, c.x);
  float w1 = a.y * fexp2(a.x - M);
  float w2 = c.y * fexp2(c.x - M);
  const float inv = 1.f / (w1 + w2);
  w1 *= inv;
  w2 *= inv;
  const uint32_t p1 = Op32[j];
  const uint32_t p2 = Op32[(1u << 21) + j];
  const float lo = w1 * __builtin_bit_cast(float, p1 << 16) +
                   w2 * __builtin_bit_cast(float, p2 << 16);
  const float hi = w1 * __builtin_bit_cast(float, p1 & 0xffff0000u) +
                   w2 * __builtin_bit_cast(float, p2 & 0xffff0000u);
  const uint32_t outw = cvt_pk_bf16(lo, hi);
  const int bh = rowid >> 11, s = rowid & 2047, b = bh >> 4, h = bh & 15;
  ((uint32_t*)AO)[((size_t)(b * 2048 + s) << 9) + h * 32 + w5] = outw;
}

// ---------------------------------------------------------------------------
extern "C" void kernel_launch(void* const* d_in, const int* in_sizes, int n_in,
                              void* d_out, int out_size, void* d_ws,
                              size_t ws_size, hipStream_t stream) {
  const float* q = (const float*)d_in[0];
  const float* k = (const float*)d_in[1];
  const float* v = (const float*)d_in[2];
  const float* w_q = (const float*)d_in[3];
  const float* b_q = (const float*)d_in[4];
  const float* w_k = (const float*)d_in[5];
  const float* b_k = (const float*)d_in[6];
  const float* w_v = (const float*)d_in[7];
  const float* b_v = (const float*)d_in[8];
  const float* w_o = (const float*)d_in[9];
  const float* b_o = (const float*)d_in[10];

  // ws layout (u16 elems): [0,12M) q/k/v bf16 (DEAD after gemm_proj; reused
  // as flash partials), [12M,16M) weights bf16, [16M,20M) Qh, [20M,24M) Kh,
  // [24M,28M) V^T, [28M,32M) attn out. 64 MB total.
  u16* ws = (u16*)d_ws;
  u16* qb = ws;                       // + z*4M for k,v
  u16* wqb = ws + (12u << 20);        // + z*1M for wk,wv (contiguous concat)
  u16* wob = ws + (15u << 20);
  u16* Qh = ws + (16u << 20);         // z=0 (pre-scaled by 0.125*log2e)
  u16* Kh = ws + (20u << 20);         // z=1
  u16* VT = ws + (24u << 20);         // z=2 (transposed)
  u16* AO = ws + (28u << 20);
  // flash partials overlay the dead q/k/v region:
  u16* Op = ws;                            // bytes [0,16MB): 2 x 4M bf16
  float2* ml = (float2*)(ws + (8u << 20)); // bytes [16,17MB): 128K float2

  cvt_all<<<dim3(8192), dim3(256), 0, stream>>>(q, k, v, w_q, w_k, w_v, w_o, ws);
  gemm_proj<<<dim3(768), dim3(512), 0, stream>>>(qb, wqb, b_q, b_k, b_v, Qh);
  flash_attn7<<<dim3(16, 32, 2), dim3(512), 0, stream>>>(Qh, Kh, VT, Op, ml);
  combine<<<dim3(8192), dim3(256), 0, stream>>>((const uint32_t*)Op, ml, AO);
  gemm_out<<<dim3(256), dim3(512), 0, stream>>>(AO, wob, b_o, (float*)d_out);
}

// Round 15
// 142.024 us; speedup vs baseline: 1.2247x; 1.0185x over previous
//
#include <hip/hip_runtime.h>
#include <hip/hip_bf16.h>
#include <stdint.h>

// Problem constants: B=2, S=2048, D_MODEL=1024, H=16, Dk=64. M = B*S = 4096.
typedef unsigned short u16;
typedef __attribute__((ext_vector_type(8))) short short8;
typedef __attribute__((ext_vector_type(8))) __bf16 bf16x8;
typedef __attribute__((ext_vector_type(4))) float f32x4;
typedef __attribute__((ext_vector_type(4))) uint32_t u32x4;

#if defined(__has_builtin)
#if __has_builtin(__builtin_amdgcn_global_load_lds)
#define USE_GLLDS 1
#endif
#endif

// Fast 2^x: v_exp_f32 is the native HW op. (__exp2f collides with glibc.)
#if defined(__has_builtin)
#if __has_builtin(__builtin_amdgcn_exp2f)
#define HAVE_EXP2_BUILTIN 1
#endif
#endif
__device__ __forceinline__ float fexp2(float x) {
#ifdef HAVE_EXP2_BUILTIN
  return __builtin_amdgcn_exp2f(x);
#else
  return exp2f(x);
#endif
}

__device__ __forceinline__ u16 f2bf(float f) {
  __hip_bfloat16 h = __float2bfloat16(f);
  return __builtin_bit_cast(u16, h);
}

// Pack 2 fp32 -> 1 u32 of 2 bf16 (RNE) in ONE instruction (T12 recipe).
__device__ __forceinline__ uint32_t cvt_pk_bf16(float lo, float hi) {
  uint32_t w;
  asm("v_cvt_pk_bf16_f32 %0, %1, %2" : "=v"(w) : "v"(lo), "v"(hi));
  return w;
}

// 8 consecutive fp32 -> short8 of bf16 (RNE; identical to __float2bfloat16).
__device__ __forceinline__ short8 pack8_f32(const float* p) {
  const float4 lo = *(const float4*)p;
  const float4 hi = *(const float4*)(p + 4);
  union { uint32_t u[4]; short8 s; } r;
  r.u[0] = cvt_pk_bf16(lo.x, lo.y);
  r.u[1] = cvt_pk_bf16(lo.z, lo.w);
  r.u[2] = cvt_pk_bf16(hi.x, hi.y);
  r.u[3] = cvt_pk_bf16(hi.z, hi.w);
  return r.s;
}

__device__ __forceinline__ f32x4 mfma16(bf16x8 a, bf16x8 b, f32x4 c) {
  return __builtin_amdgcn_mfma_f32_16x16x32_bf16(a, b, c, 0, 0, 0);
}

#ifdef USE_GLLDS
__device__ __forceinline__ void async_cp16(const void* g, void* l) {
  __builtin_amdgcn_global_load_lds(
      (const __attribute__((address_space(1))) void*)g,
      (__attribute__((address_space(3))) void*)l, 16, 0, 0);
}
#endif

// ---------------------------------------------------------------------------
// GEMM core v4: 8 waves, 128x128 tile, BK=64, single 32KB LDS buffer, T2
// XOR-swizzle (proven round 14: conflicts 14.2M -> low, 61 -> <58us), PLUS
// fused fp32->bf16 staging (A_F32/B_F32): fp32 operands are reg-staged
// (2x float4 -> 4x v_cvt_pk_bf16_f32 -> ds_write_b128, same RNE as the old
// cvt_all), bf16 operands use global_load_lds. This deletes cvt_all's 96MB
// of pure conversion traffic from the pipeline.
// LDS[row][c16] = G[row][c16 ^ (row&7)] (16B chunks); reads XOR (row&7)
// into the quad index.
// Epilogue modes:
//   0: Q  -> bf16 split-head [B,H,S,64], scaled by 0.125*log2(e)  (exp2 dom.)
//   1: K  -> bf16 split-head [B,H,S,64]
//   2: V  -> bf16 TRANSPOSED split-head [B,H,64,S]  (V^T for the PV mfma)
//   3: fp32 row-major [4096,1024] (output projection)
// W passed PRE-OFFSET to the tile's first output row; n0 = local col base.
// ---------------------------------------------------------------------------
template <int A_F32, int B_F32>
__device__ __forceinline__ void gemm_core8(const void* __restrict__ Xv,
                                           const void* __restrict__ Wv,
                                           const float* __restrict__ bias,
                                           void* __restrict__ outp, int mode,
                                           int m0, int n0) {
  __shared__ u16 Al[128 * 64];
  __shared__ u16 Bl[128 * 64];
  const int tid = threadIdx.x;
  const int wv = tid >> 6, l = tid & 63;
  const int wr = wv >> 2, wc = wv & 3;       // wave tile: rows wr*64, cols wc*32
  const int lrow = l & 15, g = l >> 4;
  const int rswe = (lrow & 7) << 3;          // read swizzle (u16 elements)

  f32x4 acc[4][2];
#pragma unroll
  for (int i = 0; i < 4; ++i)
#pragma unroll
    for (int j = 0; j < 2; ++j) acc[i][j] = (f32x4){0.f, 0.f, 0.f, 0.f};

  const int srow = l >> 3;                   // 0..7
  const int ccol = l & 7;                    // linear 16B chunk (LDS dest)
  const int gchunk = ccol ^ srow;            // inverse-swizzled source chunk
  const int arow = wv * 8 + srow;            // staged row within 128-row tile

  for (int kt = 0; kt < 1024; kt += 64) {
    // ---- stage A
    if (A_F32) {
      const float* Af = (const float*)Xv;
      const float* pa = Af + (size_t)(m0 + arow) * 1024 + kt + gchunk * 8;
      short8 a0 = pack8_f32(pa);
      short8 a1 = pack8_f32(pa + (size_t)64 * 1024);
      *(short8*)&Al[arow * 64 + ccol * 8] = a0;
      *(short8*)&Al[(arow + 64) * 64 + ccol * 8] = a1;
    } else {
      const u16* Ab = (const u16*)Xv;
      const u16* Asrc = Ab + (size_t)(m0 + arow) * 1024 + kt + gchunk * 8;
#ifdef USE_GLLDS
      async_cp16(Asrc, &Al[(wv * 8) * 64]);
      async_cp16(Asrc + (size_t)64 * 1024, &Al[(wv * 8 + 64) * 64]);
#else
      short8 a0 = *(const short8*)Asrc;
      short8 a1 = *(const short8*)(Asrc + (size_t)64 * 1024);
      *(short8*)&Al[arow * 64 + ccol * 8] = a0;
      *(short8*)&Al[(arow + 64) * 64 + ccol * 8] = a1;
#endif
    }
    // ---- stage B
    if (B_F32) {
      const float* Wf = (const float*)Wv;
      const float* pb = Wf + (size_t)arow * 1024 + kt + gchunk * 8;
      short8 b0 = pack8_f32(pb);
      short8 b1 = pack8_f32(pb + (size_t)64 * 1024);
      *(short8*)&Bl[arow * 64 + ccol * 8] = b0;
      *(short8*)&Bl[(arow + 64) * 64 + ccol * 8] = b1;
    } else {
      const u16* Wb = (const u16*)Wv;
      const u16* Bsrc = Wb + (size_t)arow * 1024 + kt + gchunk * 8;
#ifdef USE_GLLDS
      async_cp16(Bsrc, &Bl[(wv * 8) * 64]);
      async_cp16(Bsrc + (size_t)64 * 1024, &Bl[(wv * 8 + 64) * 64]);
#else
      short8 b0 = *(const short8*)Bsrc;
      short8 b1 = *(const short8*)(Bsrc + (size_t)64 * 1024);
      *(short8*)&Bl[arow * 64 + ccol * 8] = b0;
      *(short8*)&Bl[(arow + 64) * 64 + ccol * 8] = b1;
#endif
    }
    __syncthreads();   // drains staging (compiler inserts vmcnt/lgkm wait)
#pragma unroll
    for (int ks = 0; ks < 2; ++ks) {
      bf16x8 af[4], bf[2];
      const int qoff = (((ks * 4 + g) << 3) ^ rswe);  // swizzled quad offset
#pragma unroll
      for (int mf = 0; mf < 4; ++mf)
        af[mf] = *(const bf16x8*)&Al[(wr * 64 + mf * 16 + lrow) * 64 + qoff];
#pragma unroll
      for (int nf = 0; nf < 2; ++nf)
        bf[nf] = *(const bf16x8*)&Bl[(wc * 32 + nf * 16 + lrow) * 64 + qoff];
      __builtin_amdgcn_s_setprio(1);
#pragma unroll
      for (int mf = 0; mf < 4; ++mf)
#pragma unroll
        for (int nf = 0; nf < 2; ++nf)
          acc[mf][nf] = mfma16(af[mf], bf[nf], acc[mf][nf]);
      __builtin_amdgcn_s_setprio(0);
    }
    __syncthreads();   // protect buffer before next stage overwrites
  }

  const int rb = (l >> 4) * 4;
#pragma unroll
  for (int mf = 0; mf < 4; ++mf) {
#pragma unroll
    for (int nf = 0; nf < 2; ++nf) {
      const int gn = n0 + wc * 32 + nf * 16 + lrow;
      const float bi = bias[gn];
#pragma unroll
      for (int r = 0; r < 4; ++r) {
        const int gm = m0 + wr * 64 + mf * 16 + rb + r;
        float val = acc[mf][nf][r] + bi;
        const int b = gm >> 11, s = gm & 2047, h = gn >> 6, d = gn & 63;
        if (mode == 3) {
          ((float*)outp)[(size_t)gm * 1024 + gn] = val;
        } else if (mode == 2) {
          // V^T: [B,H,64,S]
          ((u16*)outp)[(((size_t)((b * 16 + h) * 64 + d)) << 11) + s] = f2bf(val);
        } else {
          if (mode == 0) val *= 0.18033688f;  // (1/8)*log2(e): exp2-domain
          ((u16*)outp)[(((size_t)((b * 16 + h) * 2048 + s)) << 6) + d] = f2bf(val);
        }
      }
    }
  }
}

// gemm_proj: fused grid over concatenated-N (N = 3072). 768 blocks; XCD-chunk
// swizzle (slot s -> xcd=s&7): chunk = 96 blocks (12 nx x 8 my). Reads fp32
// q/k/v and w_q/k/v DIRECTLY (fused conversion; cvt_all deleted).
__global__ __launch_bounds__(512, 6) void gemm_proj(
    const float* __restrict__ q, const float* __restrict__ k,
    const float* __restrict__ v, const float* __restrict__ w_q,
    const float* __restrict__ w_k, const float* __restrict__ w_v,
    const float* __restrict__ b_q, const float* __restrict__ b_k,
    const float* __restrict__ b_v, u16* __restrict__ Qh) {
  const int s = blockIdx.x;
  const int xcd = s & 7, c = s >> 3;              // c in [0,96)
  const int nx = (xcd >> 2) * 12 + (c % 12);      // [0,24)
  const int my = (xcd & 3) * 8 + (c / 12);        // [0,32)
  const int z = nx >> 3, nxl = nx & 7;
  const float* X = (z == 0) ? q : ((z == 1) ? k : v);
  const float* W = (z == 0) ? w_q : ((z == 1) ? w_k : w_v);
  const float* bias = (z == 0) ? b_q : ((z == 1) ? b_k : b_v);
  gemm_core8<1, 1>(X, W + ((size_t)nxl << 17), bias, Qh + ((size_t)z << 22),
                   z, my * 128, nxl * 128);
}

// gemm_out: 256 blocks; chunk = 32 blocks (4 nx x 8 my). A = AO bf16 (GLLDS),
// B = w_o fp32 (fused conversion).
__global__ __launch_bounds__(512, 6) void gemm_out(
    const u16* __restrict__ X, const float* __restrict__ W,
    const float* __restrict__ bias, float* __restrict__ out) {
  const int s = blockIdx.x;
  const int xcd = s & 7, c = s >> 3;              // c in [0,32)
  const int nx = (xcd >> 2) * 4 + (c & 3);        // [0,8)
  const int my = (xcd & 3) * 8 + (c >> 2);        // [0,32)
  gemm_core8<0, 1>(X, W + ((size_t)nx << 17), bias, out, 3, my * 128,
                   nx * 128);
}

// ---------------------------------------------------------------------------
// Flash attention v8: v7 (proven) + T5 s_setprio around MFMA clusters.
// v7: v5 sync structure (2 barriers per staging slot, T14 issue-early /
// write-late, single buffer per tile-half) with KVBLK=128.
// ---------------------------------------------------------------------------
__global__ __launch_bounds__(512, 4) void flash_attn8(
    const u16* __restrict__ Qh, const u16* __restrict__ Kh,
    const u16* __restrict__ VT, u16* __restrict__ Op,
    float2* __restrict__ ml) {
  __shared__ __align__(16) u16 Kbuf[2][4096];    // halves 0,1 of 128-col group
  __shared__ __align__(16) u16 Vbuf[2][4096];
  __shared__ __align__(16) uint32_t Pl[8 * 576]; // per-wave 16 rows x 36 dw

  const int tid = threadIdx.x;
  const int wv = tid >> 6, l = tid & 63;
  const int q = l & 15, g = l >> 4;

  // XCD swizzle: dispatch slot s -> original block o = (s%8)*128 + s/8.
  const int s_lin = blockIdx.x + (blockIdx.y << 4) + (blockIdx.z << 9);
  const int o = ((s_lin & 7) << 7) + (s_lin >> 3);
  const int qt = o & 15, bh = (o >> 4) & 31, z = o >> 9;

  const u16* Qp = Qh + ((size_t)bh * 2048 + qt * 128 + wv * 16) * 64;
  const u16* Kp = Kh + (size_t)bh * 2048 * 64;
  const u16* Vp = VT + (size_t)bh * 64 * 2048;

  // Q fragments (B-operand): lane holds Q[q=l&15][d = ks*32 + g*8 .. +7]
  bf16x8 qf[2];
  qf[0] = *(const bf16x8*)(Qp + q * 64 + g * 8);
  qf[1] = *(const bf16x8*)(Qp + q * 64 + 32 + g * 8);

  f32x4 o_acc[4];
#pragma unroll
  for (int df = 0; df < 4; ++df) o_acc[df] = (f32x4){0.f, 0.f, 0.f, 0.f};
  float m = -1e30f, ls = 0.f;

  const int srow = l >> 3;                       // 0..7 within wave's 8 rows
  const int scolq = (l & 7) ^ srow;              // inverse-swizzled 16B chunk
  const int pbase = wv * 576 + q * 36;
  const char* kb0 = (const char*)&Kbuf[0][0];
  const char* kb1 = (const char*)&Kbuf[1][0];
  const char* vb0 = (const char*)&Vbuf[0][0];
  const char* vb1 = (const char*)&Vbuf[1][0];
  const int rsw = (q & 7) << 4;                  // read swizzle (byte)

  // per-thread global staging pointers; a 128-col group = 128 K-rows / cols
  const u16* kg = Kp + (size_t)(z * 1024 + wv * 8 + srow) * 64 + scolq * 8;
  const u16* vg = Vp + (size_t)(wv * 8 + srow) * 2048 + z * 1024 + scolq * 8;

  // prologue: stage group 0 (both halves) through regs
  {
    short8 k0 = *(const short8*)kg;
    short8 k1 = *(const short8*)(kg + 4096);
    short8 v0 = *(const short8*)vg;
    short8 v1 = *(const short8*)(vg + 64);
    *(short8*)&Kbuf[0][wv * 512 + l * 8] = k0;
    *(short8*)&Kbuf[1][wv * 512 + l * 8] = k1;
    *(short8*)&Vbuf[0][wv * 512 + l * 8] = v0;
    *(short8*)&Vbuf[1][wv * 512 + l * 8] = v1;
  }
  kg += 8192;
  vg += 128;
  __syncthreads();

  for (int tt = 0; tt < 8; ++tt) {
    // ---- T14 issue-early: next group's loads go in flight NOW
    short8 kr0, kr1, vr0, vr1;
    if (tt < 7) {
      kr0 = *(const short8*)kg;
      kr1 = *(const short8*)(kg + 4096);
      vr0 = *(const short8*)vg;
      vr1 = *(const short8*)(vg + 64);
      kg += 8192;
      vg += 128;
    }

    // ---- S = K . Q' for both halves: sh[h][nj] holds k = h*64+nj*16+4g+r
    f32x4 s0[4], s1[4];
#pragma unroll
    for (int nj = 0; nj < 4; ++nj) {
      s0[nj] = (f32x4){0.f, 0.f, 0.f, 0.f};
      s1[nj] = (f32x4){0.f, 0.f, 0.f, 0.f};
    }
    __builtin_amdgcn_s_setprio(1);
#pragma unroll
    for (int ks = 0; ks < 2; ++ks) {
#pragma unroll
      for (int nj = 0; nj < 4; ++nj) {
        const int off = (nj * 16 + q) * 128 + (((ks * 4 + g) << 4) ^ rsw);
        bf16x8 kf0 = *(const bf16x8*)(kb0 + off);
        bf16x8 kf1 = *(const bf16x8*)(kb1 + off);
        s0[nj] = mfma16(kf0, qf[ks], s0[nj]);
        s1[nj] = mfma16(kf1, qf[ks], s1[nj]);
      }
    }
    __builtin_amdgcn_s_setprio(0);

    // ---- one online-softmax pass over all 32 values (row q, 4 lanes)
    float mt = s0[0][0];
#pragma unroll
    for (int nj = 0; nj < 4; ++nj)
#pragma unroll
      for (int r = 0; r < 4; ++r) {
        mt = fmaxf(mt, s0[nj][r]);
        mt = fmaxf(mt, s1[nj][r]);
      }
    mt = fmaxf(mt, __shfl_xor(mt, 16));
    mt = fmaxf(mt, __shfl_xor(mt, 32));
    if (!__all(mt <= m + 8.f)) {               // defer-max: rescale rarely
      const float nm = fmaxf(m, mt);
      const float rf = fexp2(m - nm);
      m = nm;
      ls *= rf;
#pragma unroll
      for (int df = 0; df < 4; ++df) o_acc[df] *= rf;
    }
    float ps = 0.f;
#pragma unroll
    for (int nj = 0; nj < 4; ++nj)
#pragma unroll
      for (int r = 0; r < 4; ++r) {
        s0[nj][r] = fexp2(s0[nj][r] - m);
        s1[nj][r] = fexp2(s1[nj][r] - m);
        ps += s0[nj][r] + s1[nj][r];
      }
    ps += __shfl_xor(ps, 16);
    ps += __shfl_xor(ps, 32);
    ls += ps;

    // ---- half 0: P -> LDS, then PV (same-wave slab, in-order DS)
#pragma unroll
    for (int nj = 0; nj < 4; ++nj)
#pragma unroll
      for (int pp = 0; pp < 2; ++pp)
        Pl[pbase + nj * 8 + g * 2 + pp] =
            cvt_pk_bf16(s0[nj][2 * pp], s0[nj][2 * pp + 1]);
    __builtin_amdgcn_s_setprio(1);
#pragma unroll
    for (int ks = 0; ks < 2; ++ks) {
      u32x4 pw = *(const u32x4*)&Pl[pbase + ks * 16 + 4 * g];
      bf16x8 pf = __builtin_bit_cast(bf16x8, pw);
#pragma unroll
      for (int df = 0; df < 4; ++df) {
        bf16x8 vf = *(const bf16x8*)(vb0 + (df * 16 + q) * 128 +
                                     (((ks * 4 + g) << 4) ^ rsw));
        o_acc[df] = mfma16(vf, pf, o_acc[df]);
      }
    }
    __builtin_amdgcn_s_setprio(0);

    // ---- half 1: P -> LDS (same addresses; true dep keeps order), then PV
#pragma unroll
    for (int nj = 0; nj < 4; ++nj)
#pragma unroll
      for (int pp = 0; pp < 2; ++pp)
        Pl[pbase + nj * 8 + g * 2 + pp] =
            cvt_pk_bf16(s1[nj][2 * pp], s1[nj][2 * pp + 1]);
    __builtin_amdgcn_s_setprio(1);
#pragma unroll
    for (int ks = 0; ks < 2; ++ks) {
      u32x4 pw = *(const u32x4*)&Pl[pbase + ks * 16 + 4 * g];
      bf16x8 pf = __builtin_bit_cast(bf16x8, pw);
#pragma unroll
      for (int df = 0; df < 4; ++df) {
        bf16x8 vf = *(const bf16x8*)(vb1 + (df * 16 + q) * 128 +
                                     (((ks * 4 + g) << 4) ^ rsw));
        o_acc[df] = mfma16(vf, pf, o_acc[df]);
      }
    }
    __builtin_amdgcn_s_setprio(0);

    // ---- v5 write-late slot: all waves done reading K/V LDS, then overwrite
    __syncthreads();
    if (tt < 7) {
      *(short8*)&Kbuf[0][wv * 512 + l * 8] = kr0;
      *(short8*)&Kbuf[1][wv * 512 + l * 8] = kr1;
      *(short8*)&Vbuf[0][wv * 512 + l * 8] = vr0;
      *(short8*)&Vbuf[1][wv * 512 + l * 8] = vr1;
    }
    __syncthreads();
  }

  // ---- epilogue: write NORMALIZED partial O (bf16) + (m, ls) per row
  const float inv = 1.f / ls;
  const int rowb = qt * 128 + wv * 16 + q;
  const size_t prow = (size_t)(z * 32 + bh) * 2048 + rowb;
  u16* Po = Op + (prow << 6);
#pragma unroll
  for (int df = 0; df < 4; ++df)
#pragma unroll
    for (int pp = 0; pp < 2; ++pp) {
      uint32_t w = cvt_pk_bf16(o_acc[df][2 * pp] * inv,
                               o_acc[df][2 * pp + 1] * inv);
      *(uint32_t*)(Po + df * 16 + 4 * g + 2 * pp) = w;
    }
  if (g == 0) ml[prow] = make_float2(m, ls);
}

// ---------------------------------------------------------------------------
// Combine the two KV-half partials: O = (w1*O1n + w2*O2n), w_i ~ ls_i*2^m_i.
// ---------------------------------------------------------------------------
__global__ __launch_bounds__(256) void combine(
    const uint32_t* __restrict__ Op32, const float2* __restrict__ ml,
    u16* __restrict__ AO) {
  const int j = blockIdx.x * 256 + threadIdx.x;   // [0, 2M)
  const int rowid = j >> 5, w5 = j & 31;
  const float2 a = ml[rowid];
  const float2 c = ml[(1 << 16) + rowid];
  const float M = fmaxf(a.x, c.x);
  float w1 = a.y * fexp2(a.x - M);
  float w2 = c.y * fexp2(c.x - M);
  const float inv = 1.f / (w1 + w2);
  w1 *= inv;
  w2 *= inv;
  const uint32_t p1 = Op32[j];
  const uint32_t p2 = Op32[(1u << 21) + j];
  const float lo = w1 * __builtin_bit_cast(float, p1 << 16) +
                   w2 * __builtin_bit_cast(float, p2 << 16);
  const float hi = w1 * __builtin_bit_cast(float, p1 & 0xffff0000u) +
                   w2 * __builtin_bit_cast(float, p2 & 0xffff0000u);
  const uint32_t outw = cvt_pk_bf16(lo, hi);
  const int bh = rowid >> 11, s = rowid & 2047, b = bh >> 4, h = bh & 15;
  ((uint32_t*)AO)[((size_t)(b * 2048 + s) << 9) + h * 32 + w5] = outw;
}

// ---------------------------------------------------------------------------
extern "C" void kernel_launch(void* const* d_in, const int* in_sizes, int n_in,
                              void* d_out, int out_size, void* d_ws,
                              size_t ws_size, hipStream_t stream) {
  const float* q = (const float*)d_in[0];
  const float* k = (const float*)d_in[1];
  const float* v = (const float*)d_in[2];
  const float* w_q = (const float*)d_in[3];
  const float* b_q = (const float*)d_in[4];
  const float* w_k = (const float*)d_in[5];
  const float* b_k = (const float*)d_in[6];
  const float* w_v = (const float*)d_in[7];
  const float* b_v = (const float*)d_in[8];
  const float* w_o = (const float*)d_in[9];
  const float* b_o = (const float*)d_in[10];

  // ws layout (u16 elems): [0,16M) flash partials (Op + ml), [16M,20M) Qh,
  // [20M,24M) Kh, [24M,28M) V^T, [28M,32M) attn out. 64 MB total.
  // (cvt_all deleted: GEMMs read fp32 inputs directly with fused conversion.)
  u16* ws = (u16*)d_ws;
  u16* Qh = ws + (16u << 20);         // z=0 (pre-scaled by 0.125*log2e)
  u16* Kh = ws + (20u << 20);         // z=1
  u16* VT = ws + (24u << 20);         // z=2 (transposed)
  u16* AO = ws + (28u << 20);
  u16* Op = ws;                            // bytes [0,16MB): 2 x 4M bf16
  float2* ml = (float2*)(ws + (8u << 20)); // bytes [16,17MB): 128K float2

  gemm_proj<<<dim3(768), dim3(512), 0, stream>>>(q, k, v, w_q, w_k, w_v, b_q,
                                                 b_k, b_v, Qh);
  flash_attn8<<<dim3(16, 32, 2), dim3(512), 0, stream>>>(Qh, Kh, VT, Op, ml);
  combine<<<dim3(8192), dim3(256), 0, stream>>>((const uint32_t*)Op, ml, AO);
  gemm_out<<<dim3(256), dim3(512), 0, stream>>>(AO, w_o, b_o, (float*)d_out);
}